// Round 10
// baseline (255.593 us; speedup 1.0000x reference)
//
#include <hip/hip_runtime.h>
#include <hip/hip_bf16.h>
#include <math.h>

// S4DConv via MFMA: B=8, L=2048, H=512, N=64, CH=1
//   k_prep:  B1' tabs + T2 tabs + u-transpose + k-row gen (one launch)
//   k_kfg:   KF rows = A_k x B1'^T -> U rows 4096+
//   k_fwd8:  256^2 deep-pipelined GEMM, epilogue fuses complex mix -> Ys
//   k_invB:  single-pass 256x128 deep-pipelined GEMM + fused skip -> out

namespace {
constexpr int cB = 8;
constexpr int cL = 2048;
constexpr int cH = 512;
constexpr int cN = 64;
constexpr int M1 = 4095;
constexpr int M2 = 4096;
constexpr int BH = cB * cH;            // 4096
constexpr int MA = BH + cH;            // 4608

constexpr size_t S0   = 2 * ((size_t)cH * cN * 6);
constexpr size_t S_B1 = S0;                           // [4096][2048] interleaved
constexpr size_t S_A  = S_B1 + (size_t)4096 * 2048;   // [4608][2048]
constexpr size_t S_T2 = S_A  + (size_t)MA * 2048;     // [2048][4096]
constexpr size_t S_U  = S_T2 + (size_t)2048 * 4096;   // [4608][4096]: rows<4096 Ys; 4096+ KF
}

typedef __attribute__((ext_vector_type(8))) short short8;
typedef __attribute__((ext_vector_type(4))) short sh4;
typedef __attribute__((ext_vector_type(4))) float f32x4;

static __device__ inline short f2bf(float x) {
    __hip_bfloat16 h = __float2bfloat16(x);
    return *reinterpret_cast<short*>(&h);
}
static __device__ inline float bf2f(short s) {
    return __uint_as_float(((unsigned int)(unsigned short)s) << 16);
}
static __device__ __forceinline__ void load_lds16(const short* g, short* l) {
    __builtin_amdgcn_global_load_lds(
        (const __attribute__((address_space(1))) void*)g,
        (__attribute__((address_space(3))) void*)l, 16, 0, 0);
}
#define WAIT_LGKM0() do { asm volatile("s_waitcnt lgkmcnt(0)" ::: "memory"); \
                          __builtin_amdgcn_sched_barrier(0); } while (0)
#define WAIT_VM(n)   do { asm volatile("s_waitcnt vmcnt(" #n ")" ::: "memory"); \
                          __builtin_amdgcn_sched_barrier(0); } while (0)
#define BAR() __builtin_amdgcn_s_barrier()

// ---- merged prep: tabs (bid<4096), u-transpose (4096..6143), k-gen (6144..6655)
__global__ __launch_bounds__(256) void k_prep(
    const float* __restrict__ u,
    const float* __restrict__ w_re, const float* __restrict__ w_im,
    const float* __restrict__ C_re, const float* __restrict__ C_im,
    const float* __restrict__ dt, short* __restrict__ Wb)
{
    __shared__ char smc[64 * 65 * 4];
    int bid = blockIdx.x, tid = threadIdx.x;
    if (bid < 2048) {                     // B1' rows
        int j  = bid;
        int t0 = tid * 8;
        int p  = (int)(((long)j * t0) % M1);
        short8 vc, vs;
#pragma unroll
        for (int i = 0; i < 8; ++i) {
            float s, c;
            sincosf((6.283185307179586f / (float)M1) * (float)p, &s, &c);
            vc[i] = f2bf(c); vs[i] = f2bf(s);
            p += j; if (p >= M1) p -= M1;
        }
        *(short8*)&Wb[S_B1 + (size_t)(2 * j)     * 2048 + t0] = vc;
        *(short8*)&Wb[S_B1 + (size_t)(2 * j + 1) * 2048 + t0] = vs;
    } else if (bid < 4096) {              // T2 rows
        int t  = bid - 2048;
        int j0 = tid * 8;
        int p  = (t * j0) & (M2 - 1);
        short8 vc, vs;
#pragma unroll
        for (int i = 0; i < 8; ++i) {
            float s, c;
            sincosf((6.283185307179586f / (float)M2) * (float)p, &s, &c);
            vc[i] = f2bf(c); vs[i] = f2bf(s);
            p = (p + t) & (M2 - 1);
        }
        *(short8*)&Wb[S_T2 + (size_t)t * 4096 + j0]        = vc;
        *(short8*)&Wb[S_T2 + (size_t)t * 4096 + 2048 + j0] = vs;
    } else if (bid < 6144) {              // u transpose -> A rows
        float (*tile)[65] = (float(*)[65])smc;
        int bid2 = bid - 4096;
        int t0 = (bid2 & 31) * 64;
        int h0 = ((bid2 >> 5) & 7) * 64;
        int b  = bid2 >> 8;
        int cx = tid & 63, r0 = tid >> 6;
#pragma unroll
        for (int i = 0; i < 16; ++i) {
            int row = r0 + i * 4;
            tile[row][cx] = u[((size_t)b * cL + t0 + row) * cH + h0 + cx];
        }
        __syncthreads();
        short* A = Wb + S_A;
#pragma unroll
        for (int i = 0; i < 16; ++i) {
            int hrow = r0 + i * 4;
            A[(size_t)(b * cH + h0 + hrow) * 2048 + t0 + cx] = f2bf(tile[cx][hrow]);
        }
    } else {                              // k-row gen (precomp inlined)
        float* md = (float*)smc;
        int h = bid - 6144;
        if (tid < cN) {
            int idx = h * cN + tid;
            double dtv = dt[h];
            double wr = w_re[idx], wi = w_im[idx];
            double ar = wr * dtv, ai = wi * dtv;
            double er = exp(ar);
            double zs, zc; sincos(ai, &zs, &zc);
            double zr = er * zc, zi = er * zs;
            double nr = zr - 1.0, ni = zi;
            double inv = 1.0 / (wr * wr + wi * wi);
            double gr = (nr * wr + ni * wi) * inv;
            double gi = (ni * wr - nr * wi) * inv;
            double cr = C_re[idx], ci = C_im[idx];
            md[tid*6+0] = (float)(cr * gr - ci * gi);
            md[tid*6+1] = (float)(cr * gi + ci * gr);
            md[tid*6+2] = (float)zr; md[tid*6+3] = (float)zi;
            md[tid*6+4] = (float)ar; md[tid*6+5] = (float)ai;
        }
        __syncthreads();
        int t0 = tid * 8;
        float acc[8] = {0.f, 0.f, 0.f, 0.f, 0.f, 0.f, 0.f, 0.f};
        for (int n = 0; n < cN; ++n) {
            float csr = md[n*6+0], csi = md[n*6+1];
            float zr  = md[n*6+2], zi  = md[n*6+3];
            float ar  = md[n*6+4], ai  = md[n*6+5];
            float mag = expf(ar * (float)t0);
            double ph = fmod((double)ai * (double)t0, 6.283185307179586);
            float s, c; sincosf((float)ph, &s, &c);
            float pr = mag * c, pi = mag * s;
#pragma unroll
            for (int i = 0; i < 8; ++i) {
                acc[i] += csr * pr - csi * pi;
                float tr = pr * zr - pi * zi;
                pi = pr * zi + pi * zr;
                pr = tr;
            }
        }
        short8 v;
#pragma unroll
        for (int i = 0; i < 8; ++i) v[i] = f2bf(2.f * acc[i]);
        *reinterpret_cast<short8*>(&Wb[S_A + (size_t)(BH + h) * 2048 + t0]) = v;
    }
}

#define MFMA16(AR, BR, ACC) \
    _Pragma("unroll") for (int kk = 0; kk < 2; ++kk) \
    _Pragma("unroll") for (int ni = 0; ni < 2; ++ni) \
    _Pragma("unroll") for (int mi = 0; mi < 4; ++mi) \
        ACC[mi][ni] = __builtin_amdgcn_mfma_f32_16x16x32_bf16(AR[mi][kk], BR[ni][kk], ACC[mi][ni], 0, 0, 0);

// ------- deep-pipelined 256x256 core (BK=64, 512 thr). Quadrants
// P0:Q00(A0,B0) P1:Q01(A0h,B1) P2:Q11(A1,B1h) P3:Q10(A1h,B0h) — h=reg-held.
// Stages one FULL tile ahead: t.P1:[A0,B0](t+2) t.P2:[B1](t+2) t.P3:[A1](t+2).
// Waits (ledger-verified): P0-end vm(10), P1-end vm(12), P3-end vm(12);
// every retired load was issued 6 phases earlier.
__device__ __forceinline__ void gemm8p_core(
    const short* __restrict__ Ag, int lda,
    const short* __restrict__ Bg, int ldb,
    int m0, int n0, int nt, short* lds, f32x4 (&acc)[4][4][2])
{
    const int tid  = threadIdx.x;
    const int wave = tid >> 6, lane = tid & 63;
    const int wm = wave >> 2, wn = wave & 3;
    const int lm = lane & 15, lk = lane >> 4;
    const int srow8 = lane >> 3;
    const int scol  = (lane & 7) * 8;

    auto stage = [&](const short* G, int ldg, int row0, int half, int kt, int sb) {
        short* l0 = lds + sb + (size_t)((kt & 1) * 2 + half) * 8192;
#pragma unroll
        for (int q = 0; q < 2; ++q) {
            int chunk = wave * 2 + q;
            int r = chunk * 8 + srow8;
            int c = scol ^ ((r & 7) << 3);
            load_lds16(G + (size_t)(row0 + half * 128 + r) * ldg + kt * 64 + c,
                       l0 + chunk * 512);
        }
    };
    auto rdA = [&](int qa, int kt, int mi, int kk) -> short8 {
        int rl = wm * 64 + mi * 16 + lm;
        int c  = (kk * 32 + lk * 8) ^ ((rl & 7) << 3);
        return *(const short8*)(lds + (size_t)((kt & 1) * 2 + qa) * 8192 + rl * 64 + c);
    };
    auto rdB = [&](int qb, int kt, int ni, int kk) -> short8 {
        int rl = wn * 32 + ni * 16 + lm;
        int c  = (kk * 32 + lk * 8) ^ ((rl & 7) << 3);
        return *(const short8*)(lds + 32768 + (size_t)((kt & 1) * 2 + qb) * 8192 + rl * 64 + c);
    };

    // prologue: tiles 0 and 1 fully staged (8 calls = 16 loads)
    stage(Ag, lda, m0, 0, 0, 0);        // A0(0)
    stage(Bg, ldb, n0, 0, 0, 32768);    // B0(0)
    stage(Bg, ldb, n0, 1, 0, 32768);    // B1(0)
    stage(Ag, lda, m0, 1, 0, 0);        // A1(0)
    stage(Ag, lda, m0, 0, 1, 0);        // A0(1)
    stage(Bg, ldb, n0, 0, 1, 32768);    // B0(1)
    stage(Bg, ldb, n0, 1, 1, 32768);    // B1(1)
    stage(Ag, lda, m0, 1, 1, 0);        // A1(1)
    WAIT_VM(12);                        // A0(0),B0(0) landed
    BAR();

    short8 a0[4][2], a1[4][2], b0[2][2], b1[2][2];
    for (int t = 0; t < nt; ++t) {
        const bool st = (t + 2 < nt);
        // ---- P0: read A0,B0 ; MFMA Q00 ----
#pragma unroll
        for (int mi = 0; mi < 4; ++mi) { a0[mi][0] = rdA(0, t, mi, 0); a0[mi][1] = rdA(0, t, mi, 1); }
#pragma unroll
        for (int ni = 0; ni < 2; ++ni) { b0[ni][0] = rdB(0, t, ni, 0); b0[ni][1] = rdB(0, t, ni, 1); }
        BAR();
        WAIT_LGKM0();
        __builtin_amdgcn_s_setprio(1);
        MFMA16(a0, b0, acc[0]);
        __builtin_amdgcn_s_setprio(0);
        if (st) { WAIT_VM(10); } else { WAIT_VM(0); }   // B1(t) landed
        BAR();
        // ---- P1: read B1 ; stage A0,B0(t+2) ; MFMA Q01 ----
#pragma unroll
        for (int ni = 0; ni < 2; ++ni) { b1[ni][0] = rdB(1, t, ni, 0); b1[ni][1] = rdB(1, t, ni, 1); }
        if (st) { stage(Ag, lda, m0, 0, t + 2, 0); stage(Bg, ldb, n0, 0, t + 2, 32768); }
        BAR();
        WAIT_LGKM0();
        __builtin_amdgcn_s_setprio(1);
        MFMA16(a0, b1, acc[1]);
        __builtin_amdgcn_s_setprio(0);
        if (st) { WAIT_VM(12); } else { WAIT_VM(0); }   // A1(t) landed
        BAR();
        // ---- P2: read A1 ; stage B1(t+2) ; MFMA Q11 ----
#pragma unroll
        for (int mi = 0; mi < 4; ++mi) { a1[mi][0] = rdA(1, t, mi, 0); a1[mi][1] = rdA(1, t, mi, 1); }
        if (st) stage(Bg, ldb, n0, 1, t + 2, 32768);
        BAR();
        WAIT_LGKM0();
        __builtin_amdgcn_s_setprio(1);
        MFMA16(a1, b1, acc[3]);
        __builtin_amdgcn_s_setprio(0);
        BAR();
        // ---- P3: stage A1(t+2) ; MFMA Q10 (regs only) ----
        if (st) stage(Ag, lda, m0, 1, t + 2, 0);
        __builtin_amdgcn_s_setprio(1);
        MFMA16(a1, b0, acc[2]);
        __builtin_amdgcn_s_setprio(0);
        if (st) { WAIT_VM(12); } else { WAIT_VM(0); }   // A0,B0(t+1) landed
        BAR();
    }
}

// forward: acc = A_u x B1'^T; fused mix epilogue -> Ys (U region rows<4096)
__global__ __launch_bounds__(512, 2) void k_fwd8(short* __restrict__ Wb)
{
    __shared__ short lds_s[65536];
    int tile = (blockIdx.x & 7) * 32 + (blockIdx.x >> 3);
    const int m0 = (tile >> 4) * 256, n0 = (tile & 15) * 256;
    const int tid = threadIdx.x;
    const int wave = tid >> 6, lane = tid & 63;
    const int wm = wave >> 2, wn = wave & 3;
    const int lm = lane & 15, lk = lane >> 4;

    f32x4 acc[4][4][2] = {};
    gemm8p_core(Wb + S_A, 2048, Wb + S_B1, 2048, m0, n0, 32, lds_s, acc);

    short* Ys = Wb + S_U;
    const short* KF = Wb + S_U;
    short (*M)[136] = (short(*)[136])lds_s;
    for (int q = 0; q < 4; ++q) {
        __syncthreads();
#pragma unroll
        for (int mi = 0; mi < 4; ++mi)
#pragma unroll
        for (int ni = 0; ni < 2; ++ni)
#pragma unroll
        for (int r = 0; r < 4; ++r)
            M[wm * 64 + mi * 16 + lk * 4 + r][wn * 32 + ni * 16 + lm] =
                f2bf(acc[q][mi][ni][r]);
        __syncthreads();
        const int jwin = (n0 >> 1) + (q & 1) * 64;
#pragma unroll
        for (int pass = 0; pass < 4; ++pass) {
            int rl = pass * 32 + (tid >> 4);
            int p0 = (tid & 15) * 4;
            int rowg = m0 + (q >> 1) * 128 + rl;
            int h = rowg & (cH - 1);
            short8 kf8 = *(const short8*)&KF[(size_t)(4096 + h) * 4096 + 2 * (jwin + p0)];
            short8 m8  = *(const short8*)&M[rl][2 * p0];
            sh4 yr4, yi4;
#pragma unroll
            for (int i = 0; i < 4; ++i) {
                float C  = bf2f(m8[2*i]),  S  = bf2f(m8[2*i+1]);
                float Ck = bf2f(kf8[2*i]), Sk = bf2f(kf8[2*i+1]);
                int j = jwin + p0 + i;
                float sc = (j == 0 ? 1.0f : 2.0f) * (1.0f / (float)M2);
                yr4[i] = f2bf(sc * (Ck * C - Sk * S));
                yi4[i] = f2bf(sc * (Ck * S + Sk * C));
            }
            *(sh4*)&Ys[(size_t)rowg * 4096 + jwin + p0]        = yr4;
            *(sh4*)&Ys[(size_t)rowg * 4096 + 2048 + jwin + p0] = yi4;
        }
    }
}

// KF rows: U[4096+h] = A_k x B1'^T
__global__ __launch_bounds__(256, 2) void k_kfg(short* __restrict__ Wb)
{
    __shared__ __align__(16) short As[128][32];
    __shared__ __align__(16) short Bs[128][32];
    const short* A = Wb + S_A;
    const short* B = Wb + S_B1;
    short* U = Wb + S_U;
    const int tid = threadIdx.x;
    const int m0 = 4096 + blockIdx.y * 128, n0 = blockIdx.x * 128;
    const int wave = tid >> 6, lane = tid & 63;
    const int wr = wave >> 1, wc = wave & 1;
    const int lm = lane & 15, lk = lane >> 4;
    const int srow = lane >> 2, scol = (lane & 3) * 8;

    f32x4 acc[4][4] = {};
    for (int k0 = 0; k0 < 2048; k0 += 32) {
        __syncthreads();
        {
            int c0 = wave * 2;
            load_lds16(&A[(size_t)(m0 + c0*16      + srow)*2048 + k0 + scol], &As[c0*16][0]);
            load_lds16(&A[(size_t)(m0 + c0*16 + 16 + srow)*2048 + k0 + scol], &As[c0*16+16][0]);
            load_lds16(&B[(size_t)(n0 + c0*16      + srow)*2048 + k0 + scol], &Bs[c0*16][0]);
            load_lds16(&B[(size_t)(n0 + c0*16 + 16 + srow)*2048 + k0 + scol], &Bs[c0*16+16][0]);
        }
        __syncthreads();
        short8 a[4];
#pragma unroll
        for (int mi = 0; mi < 4; ++mi)
            a[mi] = *(const short8*)&As[wr*64 + mi*16 + lm][lk*8];
#pragma unroll
        for (int ni = 0; ni < 4; ++ni) {
            short8 b = *(const short8*)&Bs[wc*64 + ni*16 + lm][lk*8];
#pragma unroll
            for (int mi = 0; mi < 4; ++mi)
                acc[mi][ni] = __builtin_amdgcn_mfma_f32_16x16x32_bf16(a[mi], b, acc[mi][ni], 0, 0, 0);
        }
    }
#pragma unroll
    for (int mi = 0; mi < 4; ++mi)
#pragma unroll
    for (int ni = 0; ni < 4; ++ni)
#pragma unroll
    for (int r = 0; r < 4; ++r) {
        int row = m0 + wr*64 + mi*16 + lk*4 + r;
        int col = n0 + wc*64 + ni*16 + lm;
        U[(size_t)row * 4096 + col] = f2bf(acc[mi][ni][r]);
    }
}

// inverse: BM=256(bh) x BN=128(t), K=4096, 2 phases/tile.
// LDS: A 4 half-slots (64KB) + B 3 slots (48KB) = 112KB.
// Stages: t.P0:[A1(t+1)] t.P1:[A0(t+2),B(t+3)]; waits vm(6) at both phase
// ends (ledger-verified: every retired load issued >=2 phases earlier).
__global__ __launch_bounds__(512, 1) void k_invB(const float* __restrict__ u,
                                                 const float* __restrict__ Dp,
                                                 short* __restrict__ Wb,
                                                 float* __restrict__ out)
{
    __shared__ short lds_s[57344];   // 112 KB
    int tile = (blockIdx.x & 7) * 32 + (blockIdx.x >> 3);
    const int m0 = (tile >> 4) * 256;   // bh
    const int n0 = (tile & 15) * 128;   // t
    const int tid = threadIdx.x;
    const int wave = tid >> 6, lane = tid & 63;
    const int wm = wave >> 2, wn = wave & 3;
    const int lm = lane & 15, lk = lane >> 4;
    const int srow8 = lane >> 3;
    const int scol  = (lane & 7) * 8;
    constexpr int nt = 64;
    short* lds = lds_s;
    const short* Ag = Wb + S_U;    // Ys [4096][4096]
    const short* Bg = Wb + S_T2;   // [2048][4096]

    auto stageA = [&](int half, int kt) {
        short* l0 = lds + (size_t)((kt & 1) * 2 + half) * 8192;
#pragma unroll
        for (int q = 0; q < 2; ++q) {
            int chunk = wave * 2 + q;
            int r = chunk * 8 + srow8;
            int c = scol ^ ((r & 7) << 3);
            load_lds16(Ag + (size_t)(m0 + half * 128 + r) * 4096 + kt * 64 + c,
                       l0 + chunk * 512);
        }
    };
    auto stageB = [&](int kt, int slot) {
        short* l0 = lds + 32768 + (size_t)slot * 8192;
#pragma unroll
        for (int q = 0; q < 2; ++q) {
            int chunk = wave * 2 + q;
            int r = chunk * 8 + srow8;
            int c = scol ^ ((r & 7) << 3);
            load_lds16(Bg + (size_t)(n0 + r) * 4096 + kt * 64 + c,
                       l0 + chunk * 512);
        }
    };
    auto rdA = [&](int half, int kt, int mi, int kk) -> short8 {
        int rl = wm * 64 + mi * 16 + lm;
        int c  = (kk * 32 + lk * 8) ^ ((rl & 7) << 3);
        return *(const short8*)(lds + (size_t)((kt & 1) * 2 + half) * 8192 + rl * 64 + c);
    };
    auto rdB = [&](int slot, int ni, int kk) -> short8 {
        int rl = wn * 32 + ni * 16 + lm;
        int c  = (kk * 32 + lk * 8) ^ ((rl & 7) << 3);
        return *(const short8*)(lds + 32768 + (size_t)slot * 8192 + rl * 64 + c);
    };

    f32x4 acc[2][4][2] = {};

    // prologue: A0(0),B(0),A1(0),A0(1),B(1),B(2) ; retire first 3
    stageA(0, 0);
    stageB(0, 0);
    stageA(1, 0);
    stageA(0, 1);
    stageB(1, 1);
    stageB(2, 2);
    WAIT_VM(6);
    BAR();

    short8 a[4][2], b[2][2];
    int bs = 0;                        // t % 3
    for (int t = 0; t < nt; ++t) {
        const bool deep = (t + 3 < nt);
        // ---- P0: read A0,B ; stage A1(t+1) ; MFMA Q0 ----
#pragma unroll
        for (int mi = 0; mi < 4; ++mi) { a[mi][0] = rdA(0, t, mi, 0); a[mi][1] = rdA(0, t, mi, 1); }
#pragma unroll
        for (int ni = 0; ni < 2; ++ni) { b[ni][0] = rdB(bs, ni, 0); b[ni][1] = rdB(bs, ni, 1); }
        if (t + 1 < nt) stageA(1, t + 1);
        BAR();
        WAIT_LGKM0();
        __builtin_amdgcn_s_setprio(1);
        MFMA16(a, b, acc[0]);
        __builtin_amdgcn_s_setprio(0);
        if (deep) { WAIT_VM(6); } else { WAIT_VM(0); }
        BAR();
        // ---- P1: read A1 ; stage A0(t+2), B(t+3) ; MFMA Q1 (b held) ----
#pragma unroll
        for (int mi = 0; mi < 4; ++mi) { a[mi][0] = rdA(1, t, mi, 0); a[mi][1] = rdA(1, t, mi, 1); }
        if (t + 2 < nt) stageA(0, t + 2);
        if (t + 3 < nt) stageB(t + 3, bs);     // slot (t+3)%3 == t%3
        BAR();
        WAIT_LGKM0();
        __builtin_amdgcn_s_setprio(1);
        MFMA16(a, b, acc[1]);
        __builtin_amdgcn_s_setprio(0);
        if (deep) { WAIT_VM(6); } else { WAIT_VM(0); }
        BAR();
        bs = (bs == 2) ? 0 : bs + 1;
    }

    // epilogue: transpose via LDS; coalesced 512B-run stores; fused skip
    const int b_  = m0 >> 9;
    const int h00 = m0 & 511;
    float (*T)[132] = (float(*)[132])lds_s;
#pragma unroll
    for (int q = 0; q < 2; ++q) {
        __syncthreads();
#pragma unroll
        for (int mi = 0; mi < 4; ++mi)
#pragma unroll
        for (int ni = 0; ni < 2; ++ni) {
            int tl = wn * 32 + ni * 16 + lm;
            int hl = wm * 64 + mi * 16 + lk * 4;
            *(float4*)&T[tl][hl] = *(float4*)&acc[q][mi][ni];
        }
        __syncthreads();
        int hg = h00 + q * 128 + (tid & 31) * 4;
        float4 dv = *(const float4*)&Dp[hg];
#pragma unroll
        for (int it = 0; it < 8; ++it) {
            int tl = (tid >> 5) + it * 16;
            int tg = n0 + tl;
            size_t gidx = ((size_t)b_ * cL + tg) * cH + hg;
            float4 uv = *(const float4*)&u[gidx];
            float4 yv = *(float4*)&T[tl][(tid & 31) * 4];
            yv.x += dv.x * uv.x;
            yv.y += dv.y * uv.y;
            yv.z += dv.z * uv.z;
            yv.w += dv.w * uv.w;
            *(float4*)&out[gidx] = yv;
        }
    }
}

extern "C" void kernel_launch(void* const* d_in, const int* in_sizes, int n_in,
                              void* d_out, int out_size, void* d_ws, size_t ws_size,
                              hipStream_t stream) {
    const float* u    = (const float*)d_in[0];
    const float* w_re = (const float*)d_in[1];
    const float* w_im = (const float*)d_in[2];
    const float* C_re = (const float*)d_in[3];
    const float* C_im = (const float*)d_in[4];
    const float* Dp   = (const float*)d_in[5];
    const float* dt   = (const float*)d_in[6];
    float* out = (float*)d_out;
    short* Wb  = (short*)d_ws;

    hipLaunchKernelGGL(k_prep,  dim3(6656), dim3(256), 0, stream,
                       u, w_re, w_im, C_re, C_im, dt, Wb);
    hipLaunchKernelGGL(k_kfg,   dim3(32, 4), dim3(256), 0, stream, Wb);
    hipLaunchKernelGGL(k_fwd8,  dim3(256), dim3(512), 0, stream, Wb);
    hipLaunchKernelGGL(k_invB,  dim3(256), dim3(512), 0, stream, u, Dp, Wb, out);
}

// Round 11
// 232.066 us; speedup vs baseline: 1.1014x; 1.1014x over previous
//
#include <hip/hip_runtime.h>
#include <hip/hip_bf16.h>
#include <math.h>

// S4DConv via MFMA: B=8, L=2048, H=512, N=64, CH=1
//   k_tabs:  B1' interleaved cos/sin + T2 tabs (phasor-rotation, 2 sincosf/thr)
//   k_trans: A u-rows [4096][2048] bf16 ; k_kgen: A k-rows (precomp inlined)
//   k_kfg:   KF rows = A_k x B1'^T -> U rows 4096+
//   k_fwd8:  256^2 deep-pipelined GEMM, epilogue fuses complex mix -> Ys
//   k_invB:  single-pass 256x128 deep-pipelined GEMM + fused skip -> out

namespace {
constexpr int cB = 8;
constexpr int cL = 2048;
constexpr int cH = 512;
constexpr int cN = 64;
constexpr int M1 = 4095;
constexpr int M2 = 4096;
constexpr int BH = cB * cH;            // 4096
constexpr int MA = BH + cH;            // 4608

constexpr size_t S0   = 2 * ((size_t)cH * cN * 6);
constexpr size_t S_B1 = S0;                           // [4096][2048] interleaved
constexpr size_t S_A  = S_B1 + (size_t)4096 * 2048;   // [4608][2048]
constexpr size_t S_T2 = S_A  + (size_t)MA * 2048;     // [2048][4096]
constexpr size_t S_U  = S_T2 + (size_t)2048 * 4096;   // [4608][4096]: rows<4096 Ys; 4096+ KF
}

typedef __attribute__((ext_vector_type(8))) short short8;
typedef __attribute__((ext_vector_type(4))) short sh4;
typedef __attribute__((ext_vector_type(4))) float f32x4;

static __device__ inline short f2bf(float x) {
    __hip_bfloat16 h = __float2bfloat16(x);
    return *reinterpret_cast<short*>(&h);
}
static __device__ inline float bf2f(short s) {
    return __uint_as_float(((unsigned int)(unsigned short)s) << 16);
}
static __device__ __forceinline__ void load_lds16(const short* g, short* l) {
    __builtin_amdgcn_global_load_lds(
        (const __attribute__((address_space(1))) void*)g,
        (__attribute__((address_space(3))) void*)l, 16, 0, 0);
}
#define WAIT_LGKM0() do { asm volatile("s_waitcnt lgkmcnt(0)" ::: "memory"); \
                          __builtin_amdgcn_sched_barrier(0); } while (0)
#define WAIT_VM(n)   do { asm volatile("s_waitcnt vmcnt(" #n ")" ::: "memory"); \
                          __builtin_amdgcn_sched_barrier(0); } while (0)
#define BAR() __builtin_amdgcn_s_barrier()

// tables via 2 sincosf + 8 fp32 rotations (start phase exact per thread)
__global__ __launch_bounds__(256) void k_tabs(short* __restrict__ Wb)
{
    int tid = threadIdx.x;
    if (blockIdx.x < 2048) {              // B1' rows, step j along t
        int j  = blockIdx.x;
        int t0 = tid * 8;
        int p0 = (int)(((long)j * t0) % M1);
        float c, s, cs, ss;
        sincosf((6.283185307179586f / (float)M1) * (float)p0, &s, &c);
        sincosf((6.283185307179586f / (float)M1) * (float)j,  &ss, &cs);
        short8 vc, vs;
#pragma unroll
        for (int i = 0; i < 8; ++i) {
            vc[i] = f2bf(c); vs[i] = f2bf(s);
            float tr = c * cs - s * ss;
            s = c * ss + s * cs;
            c = tr;
        }
        *(short8*)&Wb[S_B1 + (size_t)(2 * j)     * 2048 + t0] = vc;
        *(short8*)&Wb[S_B1 + (size_t)(2 * j + 1) * 2048 + t0] = vs;
    } else {                              // T2 rows, step t along j
        int t  = blockIdx.x - 2048;
        int j0 = tid * 8;
        int p0 = (t * j0) & (M2 - 1);
        float c, s, cs, ss;
        sincosf((6.283185307179586f / (float)M2) * (float)p0, &s, &c);
        sincosf((6.283185307179586f / (float)M2) * (float)t,  &ss, &cs);
        short8 vc, vs;
#pragma unroll
        for (int i = 0; i < 8; ++i) {
            vc[i] = f2bf(c); vs[i] = f2bf(s);
            float tr = c * cs - s * ss;
            s = c * ss + s * cs;
            c = tr;
        }
        *(short8*)&Wb[S_T2 + (size_t)t * 4096 + j0]        = vc;
        *(short8*)&Wb[S_T2 + (size_t)t * 4096 + 2048 + j0] = vs;
    }
}

__global__ __launch_bounds__(256) void k_trans(const float* __restrict__ u,
                                               short* __restrict__ Wb)
{
    __shared__ float tile[64][65];
    int t0 = blockIdx.x * 64;
    int h0 = blockIdx.y * 64;
    int b  = blockIdx.z;
    int cx = threadIdx.x & 63, r0 = threadIdx.x >> 6;
#pragma unroll
    for (int i = 0; i < 16; ++i) {
        int row = r0 + i * 4;
        tile[row][cx] = u[((size_t)b * cL + t0 + row) * cH + h0 + cx];
    }
    __syncthreads();
    short* A = Wb + S_A;
#pragma unroll
    for (int i = 0; i < 16; ++i) {
        int hrow = r0 + i * 4;
        A[(size_t)(b * cH + h0 + hrow) * 2048 + t0 + cx] = f2bf(tile[cx][hrow]);
    }
}

// A'[4096+h][t] = bf16(k[h][t]); per-h mode precompute inlined (threads 0..63)
__global__ __launch_bounds__(256) void k_kgen(
    const float* __restrict__ w_re, const float* __restrict__ w_im,
    const float* __restrict__ C_re, const float* __restrict__ C_im,
    const float* __restrict__ dt, short* __restrict__ Wb)
{
    __shared__ float md[cN * 6];
    int h = blockIdx.x, tid = threadIdx.x;
    if (tid < cN) {
        int idx = h * cN + tid;
        double dtv = dt[h];
        double wr = w_re[idx], wi = w_im[idx];
        double ar = wr * dtv, ai = wi * dtv;
        double er = exp(ar);
        double zs, zc; sincos(ai, &zs, &zc);
        double zr = er * zc, zi = er * zs;
        double nr = zr - 1.0, ni = zi;
        double inv = 1.0 / (wr * wr + wi * wi);
        double gr = (nr * wr + ni * wi) * inv;
        double gi = (ni * wr - nr * wi) * inv;
        double cr = C_re[idx], ci = C_im[idx];
        md[tid*6+0] = (float)(cr * gr - ci * gi);
        md[tid*6+1] = (float)(cr * gi + ci * gr);
        md[tid*6+2] = (float)zr; md[tid*6+3] = (float)zi;
        md[tid*6+4] = (float)ar; md[tid*6+5] = (float)ai;
    }
    __syncthreads();
    int t0 = tid * 8;
    float acc[8] = {0.f, 0.f, 0.f, 0.f, 0.f, 0.f, 0.f, 0.f};
    for (int n = 0; n < cN; ++n) {
        float csr = md[n*6+0], csi = md[n*6+1];
        float zr  = md[n*6+2], zi  = md[n*6+3];
        float ar  = md[n*6+4], ai  = md[n*6+5];
        float mag = expf(ar * (float)t0);
        double ph = fmod((double)ai * (double)t0, 6.283185307179586);
        float s, c; sincosf((float)ph, &s, &c);
        float pr = mag * c, pi = mag * s;
#pragma unroll
        for (int i = 0; i < 8; ++i) {
            acc[i] += csr * pr - csi * pi;
            float tr = pr * zr - pi * zi;
            pi = pr * zi + pi * zr;
            pr = tr;
        }
    }
    short8 v;
#pragma unroll
    for (int i = 0; i < 8; ++i) v[i] = f2bf(2.f * acc[i]);
    *reinterpret_cast<short8*>(&Wb[S_A + (size_t)(BH + h) * 2048 + t0]) = v;
}

#define MFMA16(AR, BR, ACC) \
    _Pragma("unroll") for (int kk = 0; kk < 2; ++kk) \
    _Pragma("unroll") for (int ni = 0; ni < 2; ++ni) \
    _Pragma("unroll") for (int mi = 0; mi < 4; ++mi) \
        ACC[mi][ni] = __builtin_amdgcn_mfma_f32_16x16x32_bf16(AR[mi][kk], BR[ni][kk], ACC[mi][ni], 0, 0, 0);

// ------- deep-pipelined 256x256 core (proven r10) ---------------------------
__device__ __forceinline__ void gemm8p_core(
    const short* __restrict__ Ag, int lda,
    const short* __restrict__ Bg, int ldb,
    int m0, int n0, int nt, short* lds, f32x4 (&acc)[4][4][2])
{
    const int tid  = threadIdx.x;
    const int wave = tid >> 6, lane = tid & 63;
    const int wm = wave >> 2, wn = wave & 3;
    const int lm = lane & 15, lk = lane >> 4;
    const int srow8 = lane >> 3;
    const int scol  = (lane & 7) * 8;

    auto stage = [&](const short* G, int ldg, int row0, int half, int kt, int sb) {
        short* l0 = lds + sb + (size_t)((kt & 1) * 2 + half) * 8192;
#pragma unroll
        for (int q = 0; q < 2; ++q) {
            int chunk = wave * 2 + q;
            int r = chunk * 8 + srow8;
            int c = scol ^ ((r & 7) << 3);
            load_lds16(G + (size_t)(row0 + half * 128 + r) * ldg + kt * 64 + c,
                       l0 + chunk * 512);
        }
    };
    auto rdA = [&](int qa, int kt, int mi, int kk) -> short8 {
        int rl = wm * 64 + mi * 16 + lm;
        int c  = (kk * 32 + lk * 8) ^ ((rl & 7) << 3);
        return *(const short8*)(lds + (size_t)((kt & 1) * 2 + qa) * 8192 + rl * 64 + c);
    };
    auto rdB = [&](int qb, int kt, int ni, int kk) -> short8 {
        int rl = wn * 32 + ni * 16 + lm;
        int c  = (kk * 32 + lk * 8) ^ ((rl & 7) << 3);
        return *(const short8*)(lds + 32768 + (size_t)((kt & 1) * 2 + qb) * 8192 + rl * 64 + c);
    };

    stage(Ag, lda, m0, 0, 0, 0);        // A0(0)
    stage(Bg, ldb, n0, 0, 0, 32768);    // B0(0)
    stage(Bg, ldb, n0, 1, 0, 32768);    // B1(0)
    stage(Ag, lda, m0, 1, 0, 0);        // A1(0)
    stage(Ag, lda, m0, 0, 1, 0);        // A0(1)
    stage(Bg, ldb, n0, 0, 1, 32768);    // B0(1)
    stage(Bg, ldb, n0, 1, 1, 32768);    // B1(1)
    stage(Ag, lda, m0, 1, 1, 0);        // A1(1)
    WAIT_VM(12);
    BAR();

    short8 a0[4][2], a1[4][2], b0[2][2], b1[2][2];
    for (int t = 0; t < nt; ++t) {
        const bool st = (t + 2 < nt);
        // ---- P0: read A0,B0 ; MFMA Q00 ----
#pragma unroll
        for (int mi = 0; mi < 4; ++mi) { a0[mi][0] = rdA(0, t, mi, 0); a0[mi][1] = rdA(0, t, mi, 1); }
#pragma unroll
        for (int ni = 0; ni < 2; ++ni) { b0[ni][0] = rdB(0, t, ni, 0); b0[ni][1] = rdB(0, t, ni, 1); }
        BAR();
        WAIT_LGKM0();
        __builtin_amdgcn_s_setprio(1);
        MFMA16(a0, b0, acc[0]);
        __builtin_amdgcn_s_setprio(0);
        if (st) { WAIT_VM(10); } else { WAIT_VM(0); }
        BAR();
        // ---- P1: read B1 ; stage A0,B0(t+2) ; MFMA Q01 ----
#pragma unroll
        for (int ni = 0; ni < 2; ++ni) { b1[ni][0] = rdB(1, t, ni, 0); b1[ni][1] = rdB(1, t, ni, 1); }
        if (st) { stage(Ag, lda, m0, 0, t + 2, 0); stage(Bg, ldb, n0, 0, t + 2, 32768); }
        BAR();
        WAIT_LGKM0();
        __builtin_amdgcn_s_setprio(1);
        MFMA16(a0, b1, acc[1]);
        __builtin_amdgcn_s_setprio(0);
        if (st) { WAIT_VM(12); } else { WAIT_VM(0); }
        BAR();
        // ---- P2: read A1 ; stage B1(t+2) ; MFMA Q11 ----
#pragma unroll
        for (int mi = 0; mi < 4; ++mi) { a1[mi][0] = rdA(1, t, mi, 0); a1[mi][1] = rdA(1, t, mi, 1); }
        if (st) stage(Bg, ldb, n0, 1, t + 2, 32768);
        BAR();
        WAIT_LGKM0();
        __builtin_amdgcn_s_setprio(1);
        MFMA16(a1, b1, acc[3]);
        __builtin_amdgcn_s_setprio(0);
        BAR();
        // ---- P3: stage A1(t+2) ; MFMA Q10 (regs only) ----
        if (st) stage(Ag, lda, m0, 1, t + 2, 0);
        __builtin_amdgcn_s_setprio(1);
        MFMA16(a1, b0, acc[2]);
        __builtin_amdgcn_s_setprio(0);
        if (st) { WAIT_VM(12); } else { WAIT_VM(0); }
        BAR();
    }
}

// forward: acc = A_u x B1'^T; fused mix epilogue -> Ys (U region rows<4096)
__global__ __launch_bounds__(512, 2) void k_fwd8(short* __restrict__ Wb)
{
    __shared__ short lds_s[65536];
    int tile = (blockIdx.x & 7) * 32 + (blockIdx.x >> 3);
    const int m0 = (tile >> 4) * 256, n0 = (tile & 15) * 256;
    const int tid = threadIdx.x;
    const int wave = tid >> 6, lane = tid & 63;
    const int wm = wave >> 2, wn = wave & 3;
    const int lm = lane & 15, lk = lane >> 4;

    f32x4 acc[4][4][2] = {};
    gemm8p_core(Wb + S_A, 2048, Wb + S_B1, 2048, m0, n0, 32, lds_s, acc);

    short* Ys = Wb + S_U;
    const short* KF = Wb + S_U;
    short (*M)[136] = (short(*)[136])lds_s;
    for (int q = 0; q < 4; ++q) {
        __syncthreads();
#pragma unroll
        for (int mi = 0; mi < 4; ++mi)
#pragma unroll
        for (int ni = 0; ni < 2; ++ni)
#pragma unroll
        for (int r = 0; r < 4; ++r)
            M[wm * 64 + mi * 16 + lk * 4 + r][wn * 32 + ni * 16 + lm] =
                f2bf(acc[q][mi][ni][r]);
        __syncthreads();
        const int jwin = (n0 >> 1) + (q & 1) * 64;
#pragma unroll
        for (int pass = 0; pass < 4; ++pass) {
            int rl = pass * 32 + (tid >> 4);
            int p0 = (tid & 15) * 4;
            int rowg = m0 + (q >> 1) * 128 + rl;
            int h = rowg & (cH - 1);
            short8 kf8 = *(const short8*)&KF[(size_t)(4096 + h) * 4096 + 2 * (jwin + p0)];
            short8 m8  = *(const short8*)&M[rl][2 * p0];
            sh4 yr4, yi4;
#pragma unroll
            for (int i = 0; i < 4; ++i) {
                float C  = bf2f(m8[2*i]),  S  = bf2f(m8[2*i+1]);
                float Ck = bf2f(kf8[2*i]), Sk = bf2f(kf8[2*i+1]);
                int j = jwin + p0 + i;
                float sc = (j == 0 ? 1.0f : 2.0f) * (1.0f / (float)M2);
                yr4[i] = f2bf(sc * (Ck * C - Sk * S));
                yi4[i] = f2bf(sc * (Ck * S + Sk * C));
            }
            *(sh4*)&Ys[(size_t)rowg * 4096 + jwin + p0]        = yr4;
            *(sh4*)&Ys[(size_t)rowg * 4096 + 2048 + jwin + p0] = yi4;
        }
    }
}

// KF rows: U[4096+h] = A_k x B1'^T
__global__ __launch_bounds__(256, 2) void k_kfg(short* __restrict__ Wb)
{
    __shared__ __align__(16) short As[128][32];
    __shared__ __align__(16) short Bs[128][32];
    const short* A = Wb + S_A;
    const short* B = Wb + S_B1;
    short* U = Wb + S_U;
    const int tid = threadIdx.x;
    const int m0 = 4096 + blockIdx.y * 128, n0 = blockIdx.x * 128;
    const int wave = tid >> 6, lane = tid & 63;
    const int wr = wave >> 1, wc = wave & 1;
    const int lm = lane & 15, lk = lane >> 4;
    const int srow = lane >> 2, scol = (lane & 3) * 8;

    f32x4 acc[4][4] = {};
    for (int k0 = 0; k0 < 2048; k0 += 32) {
        __syncthreads();
        {
            int c0 = wave * 2;
            load_lds16(&A[(size_t)(m0 + c0*16      + srow)*2048 + k0 + scol], &As[c0*16][0]);
            load_lds16(&A[(size_t)(m0 + c0*16 + 16 + srow)*2048 + k0 + scol], &As[c0*16+16][0]);
            load_lds16(&B[(size_t)(n0 + c0*16      + srow)*2048 + k0 + scol], &Bs[c0*16][0]);
            load_lds16(&B[(size_t)(n0 + c0*16 + 16 + srow)*2048 + k0 + scol], &Bs[c0*16+16][0]);
        }
        __syncthreads();
        short8 a[4];
#pragma unroll
        for (int mi = 0; mi < 4; ++mi)
            a[mi] = *(const short8*)&As[wr*64 + mi*16 + lm][lk*8];
#pragma unroll
        for (int ni = 0; ni < 4; ++ni) {
            short8 b = *(const short8*)&Bs[wc*64 + ni*16 + lm][lk*8];
#pragma unroll
            for (int mi = 0; mi < 4; ++mi)
                acc[mi][ni] = __builtin_amdgcn_mfma_f32_16x16x32_bf16(a[mi], b, acc[mi][ni], 0, 0, 0);
        }
    }
#pragma unroll
    for (int mi = 0; mi < 4; ++mi)
#pragma unroll
    for (int ni = 0; ni < 4; ++ni)
#pragma unroll
    for (int r = 0; r < 4; ++r) {
        int row = m0 + wr*64 + mi*16 + lk*4 + r;
        int col = n0 + wc*64 + ni*16 + lm;
        U[(size_t)row * 4096 + col] = f2bf(acc[mi][ni][r]);
    }
}

// inverse: BM=256 x BN=128, K=4096, deep 3-slot B pipeline (proven r10)
__global__ __launch_bounds__(512, 1) void k_invB(const float* __restrict__ u,
                                                 const float* __restrict__ Dp,
                                                 short* __restrict__ Wb,
                                                 float* __restrict__ out)
{
    __shared__ short lds_s[57344];   // 112 KB
    int tile = (blockIdx.x & 7) * 32 + (blockIdx.x >> 3);
    const int m0 = (tile >> 4) * 256;   // bh
    const int n0 = (tile & 15) * 128;   // t
    const int tid = threadIdx.x;
    const int wave = tid >> 6, lane = tid & 63;
    const int wm = wave >> 2, wn = wave & 3;
    const int lm = lane & 15, lk = lane >> 4;
    const int srow8 = lane >> 3;
    const int scol  = (lane & 7) * 8;
    constexpr int nt = 64;
    short* lds = lds_s;
    const short* Ag = Wb + S_U;    // Ys [4096][4096]
    const short* Bg = Wb + S_T2;   // [2048][4096]

    auto stageA = [&](int half, int kt) {
        short* l0 = lds + (size_t)((kt & 1) * 2 + half) * 8192;
#pragma unroll
        for (int q = 0; q < 2; ++q) {
            int chunk = wave * 2 + q;
            int r = chunk * 8 + srow8;
            int c = scol ^ ((r & 7) << 3);
            load_lds16(Ag + (size_t)(m0 + half * 128 + r) * 4096 + kt * 64 + c,
                       l0 + chunk * 512);
        }
    };
    auto stageB = [&](int kt, int slot) {
        short* l0 = lds + 32768 + (size_t)slot * 8192;
#pragma unroll
        for (int q = 0; q < 2; ++q) {
            int chunk = wave * 2 + q;
            int r = chunk * 8 + srow8;
            int c = scol ^ ((r & 7) << 3);
            load_lds16(Bg + (size_t)(n0 + r) * 4096 + kt * 64 + c,
                       l0 + chunk * 512);
        }
    };
    auto rdA = [&](int half, int kt, int mi, int kk) -> short8 {
        int rl = wm * 64 + mi * 16 + lm;
        int c  = (kk * 32 + lk * 8) ^ ((rl & 7) << 3);
        return *(const short8*)(lds + (size_t)((kt & 1) * 2 + half) * 8192 + rl * 64 + c);
    };
    auto rdB = [&](int slot, int ni, int kk) -> short8 {
        int rl = wn * 32 + ni * 16 + lm;
        int c  = (kk * 32 + lk * 8) ^ ((rl & 7) << 3);
        return *(const short8*)(lds + 32768 + (size_t)slot * 8192 + rl * 64 + c);
    };

    f32x4 acc[2][4][2] = {};

    stageA(0, 0);
    stageB(0, 0);
    stageA(1, 0);
    stageA(0, 1);
    stageB(1, 1);
    stageB(2, 2);
    WAIT_VM(6);
    BAR();

    short8 a[4][2], b[2][2];
    int bs = 0;
    for (int t = 0; t < nt; ++t) {
        const bool deep = (t + 3 < nt);
        // ---- P0 ----
#pragma unroll
        for (int mi = 0; mi < 4; ++mi) { a[mi][0] = rdA(0, t, mi, 0); a[mi][1] = rdA(0, t, mi, 1); }
#pragma unroll
        for (int ni = 0; ni < 2; ++ni) { b[ni][0] = rdB(bs, ni, 0); b[ni][1] = rdB(bs, ni, 1); }
        if (t + 1 < nt) stageA(1, t + 1);
        BAR();
        WAIT_LGKM0();
        __builtin_amdgcn_s_setprio(1);
        MFMA16(a, b, acc[0]);
        __builtin_amdgcn_s_setprio(0);
        if (deep) { WAIT_VM(6); } else { WAIT_VM(0); }
        BAR();
        // ---- P1 ----
#pragma unroll
        for (int mi = 0; mi < 4; ++mi) { a[mi][0] = rdA(1, t, mi, 0); a[mi][1] = rdA(1, t, mi, 1); }
        if (t + 2 < nt) stageA(0, t + 2);
        if (t + 3 < nt) stageB(t + 3, bs);
        BAR();
        WAIT_LGKM0();
        __builtin_amdgcn_s_setprio(1);
        MFMA16(a, b, acc[1]);
        __builtin_amdgcn_s_setprio(0);
        if (deep) { WAIT_VM(6); } else { WAIT_VM(0); }
        BAR();
        bs = (bs == 2) ? 0 : bs + 1;
    }

    const int b_  = m0 >> 9;
    const int h00 = m0 & 511;
    float (*T)[132] = (float(*)[132])lds_s;
#pragma unroll
    for (int q = 0; q < 2; ++q) {
        __syncthreads();
#pragma unroll
        for (int mi = 0; mi < 4; ++mi)
#pragma unroll
        for (int ni = 0; ni < 2; ++ni) {
            int tl = wn * 32 + ni * 16 + lm;
            int hl = wm * 64 + mi * 16 + lk * 4;
            *(float4*)&T[tl][hl] = *(float4*)&acc[q][mi][ni];
        }
        __syncthreads();
        int hg = h00 + q * 128 + (tid & 31) * 4;
        float4 dv = *(const float4*)&Dp[hg];
#pragma unroll
        for (int it = 0; it < 8; ++it) {
            int tl = (tid >> 5) + it * 16;
            int tg = n0 + tl;
            size_t gidx = ((size_t)b_ * cL + tg) * cH + hg;
            float4 uv = *(const float4*)&u[gidx];
            float4 yv = *(float4*)&T[tl][(tid & 31) * 4];
            yv.x += dv.x * uv.x;
            yv.y += dv.y * uv.y;
            yv.z += dv.z * uv.z;
            yv.w += dv.w * uv.w;
            *(float4*)&out[gidx] = yv;
        }
    }
}

extern "C" void kernel_launch(void* const* d_in, const int* in_sizes, int n_in,
                              void* d_out, int out_size, void* d_ws, size_t ws_size,
                              hipStream_t stream) {
    const float* u    = (const float*)d_in[0];
    const float* w_re = (const float*)d_in[1];
    const float* w_im = (const float*)d_in[2];
    const float* C_re = (const float*)d_in[3];
    const float* C_im = (const float*)d_in[4];
    const float* Dp   = (const float*)d_in[5];
    const float* dt   = (const float*)d_in[6];
    float* out = (float*)d_out;
    short* Wb  = (short*)d_ws;

    hipLaunchKernelGGL(k_tabs,  dim3(4096), dim3(256), 0, stream, Wb);
    hipLaunchKernelGGL(k_trans, dim3(cL / 64, cH / 64, cB), dim3(256), 0, stream, u, Wb);
    hipLaunchKernelGGL(k_kgen,  dim3(cH), dim3(256), 0, stream,
                       w_re, w_im, C_re, C_im, dt, Wb);
    hipLaunchKernelGGL(k_kfg,   dim3(32, 4), dim3(256), 0, stream, Wb);
    hipLaunchKernelGGL(k_fwd8,  dim3(256), dim3(512), 0, stream, Wb);
    hipLaunchKernelGGL(k_invB,  dim3(256), dim3(512), 0, stream, u, Dp, Wb, out);
}

// Round 12
// 212.612 us; speedup vs baseline: 1.2022x; 1.0915x over previous
//
#include <hip/hip_runtime.h>
#include <hip/hip_bf16.h>
#include <math.h>

// S4DConv via MFMA: B=8, L=2048, H=512, N=64, CH=1
//   k_tabs:  B1' interleaved cos/sin + B2 parity tables [2][1024][2048]
//   k_trans: A u-rows; k_kgen: A k-rows
//   k_kfg:   KF rows = A_k x B1'^T -> U rows 4096+
//   k_fwd8:  256^2 deep-pipelined GEMM, epilogue fuses complex mix -> Ys
//   k_par:   parity fold: Ae/Ao[bh][2048] from Ys row (j-mirror symmetry)
//   k_invB:  y[2tau+p] = Apar_p x B2_p^T (K=2048) + fused skip -> out

namespace {
constexpr int cB = 8;
constexpr int cL = 2048;
constexpr int cH = 512;
constexpr int cN = 64;
constexpr int M1 = 4095;
constexpr int M2 = 4096;
constexpr int BH = cB * cH;            // 4096
constexpr int MA = BH + cH;            // 4608

constexpr size_t S0   = 2 * ((size_t)cH * cN * 6);
constexpr size_t S_B1 = S0;                           // [4096][2048]; Apar [2][4096][2048] overlays after fwd8
constexpr size_t S_A  = S_B1 + (size_t)4096 * 2048;   // [4608][2048]
constexpr size_t S_T2 = S_A  + (size_t)MA * 2048;     // B2 [2][1024][2048]
constexpr size_t S_U  = S_T2 + (size_t)2048 * 4096;   // [4608][4096]: rows<4096 Ys; 4096+ KF
constexpr size_t S_AP = S_B1;                         // Apar overlay (B1+A dead)
}

typedef __attribute__((ext_vector_type(8))) short short8;
typedef __attribute__((ext_vector_type(4))) short sh4;
typedef __attribute__((ext_vector_type(4))) float f32x4;

static __device__ inline short f2bf(float x) {
    __hip_bfloat16 h = __float2bfloat16(x);
    return *reinterpret_cast<short*>(&h);
}
static __device__ inline float bf2f(short s) {
    return __uint_as_float(((unsigned int)(unsigned short)s) << 16);
}
static __device__ __forceinline__ void load_lds16(const short* g, short* l) {
    __builtin_amdgcn_global_load_lds(
        (const __attribute__((address_space(1))) void*)g,
        (__attribute__((address_space(3))) void*)l, 16, 0, 0);
}
#define WAIT_LGKM0() do { asm volatile("s_waitcnt lgkmcnt(0)" ::: "memory"); \
                          __builtin_amdgcn_sched_barrier(0); } while (0)
#define WAIT_VM(n)   do { asm volatile("s_waitcnt vmcnt(" #n ")" ::: "memory"); \
                          __builtin_amdgcn_sched_barrier(0); } while (0)
#define BAR() __builtin_amdgcn_s_barrier()

// blocks 0..2047: B1' rows (cos/sin interleave over j)
// blocks 2048..4095: B2 parity rows: r=bid-2048, p=r>>10, tau=r&1023, t=2tau+p
//   k==0:1 ; k in[1,1024): cos(2pi k t/4096) ; k in[1024,2047): sin(2pi (k-1023) t/4096)
//   k==2047: (-1)^tau  (j=1024 slot; cos for even t, sin for odd t — both (-1)^tau)
__global__ __launch_bounds__(256) void k_tabs(short* __restrict__ Wb)
{
    int tid = threadIdx.x;
    if (blockIdx.x < 2048) {
        int j  = blockIdx.x;
        int t0 = tid * 8;
        int p0 = (int)(((long)j * t0) % M1);
        float c, s, cs, ss;
        sincosf((6.283185307179586f / (float)M1) * (float)p0, &s, &c);
        sincosf((6.283185307179586f / (float)M1) * (float)j,  &ss, &cs);
        short8 vc, vs;
#pragma unroll
        for (int i = 0; i < 8; ++i) {
            vc[i] = f2bf(c); vs[i] = f2bf(s);
            float tr = c * cs - s * ss;
            s = c * ss + s * cs;
            c = tr;
        }
        *(short8*)&Wb[S_B1 + (size_t)(2 * j)     * 2048 + t0] = vc;
        *(short8*)&Wb[S_B1 + (size_t)(2 * j + 1) * 2048 + t0] = vs;
    } else {
        int r   = blockIdx.x - 2048;
        int p   = r >> 10, tau = r & 1023;
        int t   = 2 * tau + p;
        int k0  = tid * 8;
        float stepang = (6.283185307179586f / (float)M2) * (float)t;
        float cs, ss; sincosf(stepang, &ss, &cs);
        short8 v;
        if (k0 < 1024) {          // cos chunk
            int ph = (k0 * t) & (M2 - 1);
            float c, s; sincosf((6.283185307179586f / (float)M2) * (float)ph, &s, &c);
#pragma unroll
            for (int i = 0; i < 8; ++i) {
                v[i] = f2bf(c);
                float tr = c * cs - s * ss;
                s = c * ss + s * cs;
                c = tr;
            }
        } else {                  // sin chunk (j = k-1023), last slot special
            int j0 = k0 - 1023;
            int ph = (j0 * t) & (M2 - 1);
            float c, s; sincosf((6.283185307179586f / (float)M2) * (float)ph, &s, &c);
#pragma unroll
            for (int i = 0; i < 8; ++i) {
                int k = k0 + i;
                v[i] = (k == 2047) ? f2bf((tau & 1) ? -1.f : 1.f) : f2bf(s);
                float tr = c * cs - s * ss;
                s = c * ss + s * cs;
                c = tr;
            }
        }
        *(short8*)&Wb[S_T2 + (size_t)r * 2048 + k0] = v;
    }
}

__global__ __launch_bounds__(256) void k_trans(const float* __restrict__ u,
                                               short* __restrict__ Wb)
{
    __shared__ float tile[64][65];
    int t0 = blockIdx.x * 64;
    int h0 = blockIdx.y * 64;
    int b  = blockIdx.z;
    int cx = threadIdx.x & 63, r0 = threadIdx.x >> 6;
#pragma unroll
    for (int i = 0; i < 16; ++i) {
        int row = r0 + i * 4;
        tile[row][cx] = u[((size_t)b * cL + t0 + row) * cH + h0 + cx];
    }
    __syncthreads();
    short* A = Wb + S_A;
#pragma unroll
    for (int i = 0; i < 16; ++i) {
        int hrow = r0 + i * 4;
        A[(size_t)(b * cH + h0 + hrow) * 2048 + t0 + cx] = f2bf(tile[cx][hrow]);
    }
}

__global__ __launch_bounds__(256) void k_kgen(
    const float* __restrict__ w_re, const float* __restrict__ w_im,
    const float* __restrict__ C_re, const float* __restrict__ C_im,
    const float* __restrict__ dt, short* __restrict__ Wb)
{
    __shared__ float md[cN * 6];
    int h = blockIdx.x, tid = threadIdx.x;
    if (tid < cN) {
        int idx = h * cN + tid;
        double dtv = dt[h];
        double wr = w_re[idx], wi = w_im[idx];
        double ar = wr * dtv, ai = wi * dtv;
        double er = exp(ar);
        double zs, zc; sincos(ai, &zs, &zc);
        double zr = er * zc, zi = er * zs;
        double nr = zr - 1.0, ni = zi;
        double inv = 1.0 / (wr * wr + wi * wi);
        double gr = (nr * wr + ni * wi) * inv;
        double gi = (ni * wr - nr * wi) * inv;
        double cr = C_re[idx], ci = C_im[idx];
        md[tid*6+0] = (float)(cr * gr - ci * gi);
        md[tid*6+1] = (float)(cr * gi + ci * gr);
        md[tid*6+2] = (float)zr; md[tid*6+3] = (float)zi;
        md[tid*6+4] = (float)ar; md[tid*6+5] = (float)ai;
    }
    __syncthreads();
    int t0 = tid * 8;
    float acc[8] = {0.f, 0.f, 0.f, 0.f, 0.f, 0.f, 0.f, 0.f};
    for (int n = 0; n < cN; ++n) {
        float csr = md[n*6+0], csi = md[n*6+1];
        float zr  = md[n*6+2], zi  = md[n*6+3];
        float ar  = md[n*6+4], ai  = md[n*6+5];
        float mag = expf(ar * (float)t0);
        double ph = fmod((double)ai * (double)t0, 6.283185307179586);
        float s, c; sincosf((float)ph, &s, &c);
        float pr = mag * c, pi = mag * s;
#pragma unroll
        for (int i = 0; i < 8; ++i) {
            acc[i] += csr * pr - csi * pi;
            float tr = pr * zr - pi * zi;
            pi = pr * zi + pi * zr;
            pr = tr;
        }
    }
    short8 v;
#pragma unroll
    for (int i = 0; i < 8; ++i) v[i] = f2bf(2.f * acc[i]);
    *reinterpret_cast<short8*>(&Wb[S_A + (size_t)(BH + h) * 2048 + t0]) = v;
}

#define MFMA16(AR, BR, ACC) \
    _Pragma("unroll") for (int kk = 0; kk < 2; ++kk) \
    _Pragma("unroll") for (int ni = 0; ni < 2; ++ni) \
    _Pragma("unroll") for (int mi = 0; mi < 4; ++mi) \
        ACC[mi][ni] = __builtin_amdgcn_mfma_f32_16x16x32_bf16(AR[mi][kk], BR[ni][kk], ACC[mi][ni], 0, 0, 0);

// ------- deep-pipelined 256x256 core (proven r10/r11) -----------------------
__device__ __forceinline__ void gemm8p_core(
    const short* __restrict__ Ag, int lda,
    const short* __restrict__ Bg, int ldb,
    int m0, int n0, int nt, short* lds, f32x4 (&acc)[4][4][2])
{
    const int tid  = threadIdx.x;
    const int wave = tid >> 6, lane = tid & 63;
    const int wm = wave >> 2, wn = wave & 3;
    const int lm = lane & 15, lk = lane >> 4;
    const int srow8 = lane >> 3;
    const int scol  = (lane & 7) * 8;

    auto stage = [&](const short* G, int ldg, int row0, int half, int kt, int sb) {
        short* l0 = lds + sb + (size_t)((kt & 1) * 2 + half) * 8192;
#pragma unroll
        for (int q = 0; q < 2; ++q) {
            int chunk = wave * 2 + q;
            int r = chunk * 8 + srow8;
            int c = scol ^ ((r & 7) << 3);
            load_lds16(G + (size_t)(row0 + half * 128 + r) * ldg + kt * 64 + c,
                       l0 + chunk * 512);
        }
    };
    auto rdA = [&](int qa, int kt, int mi, int kk) -> short8 {
        int rl = wm * 64 + mi * 16 + lm;
        int c  = (kk * 32 + lk * 8) ^ ((rl & 7) << 3);
        return *(const short8*)(lds + (size_t)((kt & 1) * 2 + qa) * 8192 + rl * 64 + c);
    };
    auto rdB = [&](int qb, int kt, int ni, int kk) -> short8 {
        int rl = wn * 32 + ni * 16 + lm;
        int c  = (kk * 32 + lk * 8) ^ ((rl & 7) << 3);
        return *(const short8*)(lds + 32768 + (size_t)((kt & 1) * 2 + qb) * 8192 + rl * 64 + c);
    };

    stage(Ag, lda, m0, 0, 0, 0);
    stage(Bg, ldb, n0, 0, 0, 32768);
    stage(Bg, ldb, n0, 1, 0, 32768);
    stage(Ag, lda, m0, 1, 0, 0);
    stage(Ag, lda, m0, 0, 1, 0);
    stage(Bg, ldb, n0, 0, 1, 32768);
    stage(Bg, ldb, n0, 1, 1, 32768);
    stage(Ag, lda, m0, 1, 1, 0);
    WAIT_VM(12);
    BAR();

    short8 a0[4][2], a1[4][2], b0[2][2], b1[2][2];
    for (int t = 0; t < nt; ++t) {
        const bool st = (t + 2 < nt);
        // ---- P0 ----
#pragma unroll
        for (int mi = 0; mi < 4; ++mi) { a0[mi][0] = rdA(0, t, mi, 0); a0[mi][1] = rdA(0, t, mi, 1); }
#pragma unroll
        for (int ni = 0; ni < 2; ++ni) { b0[ni][0] = rdB(0, t, ni, 0); b0[ni][1] = rdB(0, t, ni, 1); }
        BAR();
        WAIT_LGKM0();
        __builtin_amdgcn_s_setprio(1);
        MFMA16(a0, b0, acc[0]);
        __builtin_amdgcn_s_setprio(0);
        if (st) { WAIT_VM(10); } else { WAIT_VM(0); }
        BAR();
        // ---- P1 ----
#pragma unroll
        for (int ni = 0; ni < 2; ++ni) { b1[ni][0] = rdB(1, t, ni, 0); b1[ni][1] = rdB(1, t, ni, 1); }
        if (st) { stage(Ag, lda, m0, 0, t + 2, 0); stage(Bg, ldb, n0, 0, t + 2, 32768); }
        BAR();
        WAIT_LGKM0();
        __builtin_amdgcn_s_setprio(1);
        MFMA16(a0, b1, acc[1]);
        __builtin_amdgcn_s_setprio(0);
        if (st) { WAIT_VM(12); } else { WAIT_VM(0); }
        BAR();
        // ---- P2 ----
#pragma unroll
        for (int mi = 0; mi < 4; ++mi) { a1[mi][0] = rdA(1, t, mi, 0); a1[mi][1] = rdA(1, t, mi, 1); }
        if (st) stage(Bg, ldb, n0, 1, t + 2, 32768);
        BAR();
        WAIT_LGKM0();
        __builtin_amdgcn_s_setprio(1);
        MFMA16(a1, b1, acc[3]);
        __builtin_amdgcn_s_setprio(0);
        BAR();
        // ---- P3 ----
        if (st) stage(Ag, lda, m0, 1, t + 2, 0);
        __builtin_amdgcn_s_setprio(1);
        MFMA16(a1, b0, acc[2]);
        __builtin_amdgcn_s_setprio(0);
        if (st) { WAIT_VM(12); } else { WAIT_VM(0); }
        BAR();
    }
}

// forward: acc = A_u x B1'^T; fused mix epilogue -> Ys (U region rows<4096)
__global__ __launch_bounds__(512, 2) void k_fwd8(short* __restrict__ Wb)
{
    __shared__ short lds_s[65536];
    int tile = (blockIdx.x & 7) * 32 + (blockIdx.x >> 3);
    const int m0 = (tile >> 4) * 256, n0 = (tile & 15) * 256;
    const int tid = threadIdx.x;
    const int wave = tid >> 6, lane = tid & 63;
    const int wm = wave >> 2, wn = wave & 3;
    const int lm = lane & 15, lk = lane >> 4;

    f32x4 acc[4][4][2] = {};
    gemm8p_core(Wb + S_A, 2048, Wb + S_B1, 2048, m0, n0, 32, lds_s, acc);

    short* Ys = Wb + S_U;
    const short* KF = Wb + S_U;
    short (*M)[136] = (short(*)[136])lds_s;
    for (int q = 0; q < 4; ++q) {
        __syncthreads();
#pragma unroll
        for (int mi = 0; mi < 4; ++mi)
#pragma unroll
        for (int ni = 0; ni < 2; ++ni)
#pragma unroll
        for (int r = 0; r < 4; ++r)
            M[wm * 64 + mi * 16 + lk * 4 + r][wn * 32 + ni * 16 + lm] =
                f2bf(acc[q][mi][ni][r]);
        __syncthreads();
        const int jwin = (n0 >> 1) + (q & 1) * 64;
#pragma unroll
        for (int pass = 0; pass < 4; ++pass) {
            int rl = pass * 32 + (tid >> 4);
            int p0 = (tid & 15) * 4;
            int rowg = m0 + (q >> 1) * 128 + rl;
            int h = rowg & (cH - 1);
            short8 kf8 = *(const short8*)&KF[(size_t)(4096 + h) * 4096 + 2 * (jwin + p0)];
            short8 m8  = *(const short8*)&M[rl][2 * p0];
            sh4 yr4, yi4;
#pragma unroll
            for (int i = 0; i < 4; ++i) {
                float C  = bf2f(m8[2*i]),  S  = bf2f(m8[2*i+1]);
                float Ck = bf2f(kf8[2*i]), Sk = bf2f(kf8[2*i+1]);
                int j = jwin + p0 + i;
                float sc = (j == 0 ? 1.0f : 2.0f) * (1.0f / (float)M2);
                yr4[i] = f2bf(sc * (Ck * C - Sk * S));
                yi4[i] = f2bf(sc * (Ck * S + Sk * C));
            }
            *(sh4*)&Ys[(size_t)rowg * 4096 + jwin + p0]        = yr4;
            *(sh4*)&Ys[(size_t)rowg * 4096 + 2048 + jwin + p0] = yi4;
        }
    }
}

// KF rows: U[4096+h] = A_k x B1'^T
__global__ __launch_bounds__(256, 2) void k_kfg(short* __restrict__ Wb)
{
    __shared__ __align__(16) short As[128][32];
    __shared__ __align__(16) short Bs[128][32];
    const short* A = Wb + S_A;
    const short* B = Wb + S_B1;
    short* U = Wb + S_U;
    const int tid = threadIdx.x;
    const int m0 = 4096 + blockIdx.y * 128, n0 = blockIdx.x * 128;
    const int wave = tid >> 6, lane = tid & 63;
    const int wr = wave >> 1, wc = wave & 1;
    const int lm = lane & 15, lk = lane >> 4;
    const int srow = lane >> 2, scol = (lane & 3) * 8;

    f32x4 acc[4][4] = {};
    for (int k0 = 0; k0 < 2048; k0 += 32) {
        __syncthreads();
        {
            int c0 = wave * 2;
            load_lds16(&A[(size_t)(m0 + c0*16      + srow)*2048 + k0 + scol], &As[c0*16][0]);
            load_lds16(&A[(size_t)(m0 + c0*16 + 16 + srow)*2048 + k0 + scol], &As[c0*16+16][0]);
            load_lds16(&B[(size_t)(n0 + c0*16      + srow)*2048 + k0 + scol], &Bs[c0*16][0]);
            load_lds16(&B[(size_t)(n0 + c0*16 + 16 + srow)*2048 + k0 + scol], &Bs[c0*16+16][0]);
        }
        __syncthreads();
        short8 a[4];
#pragma unroll
        for (int mi = 0; mi < 4; ++mi)
            a[mi] = *(const short8*)&As[wr*64 + mi*16 + lm][lk*8];
#pragma unroll
        for (int ni = 0; ni < 4; ++ni) {
            short8 b = *(const short8*)&Bs[wc*64 + ni*16 + lm][lk*8];
#pragma unroll
            for (int mi = 0; mi < 4; ++mi)
                acc[mi][ni] = __builtin_amdgcn_mfma_f32_16x16x32_bf16(a[mi], b, acc[mi][ni], 0, 0, 0);
        }
    }
#pragma unroll
    for (int mi = 0; mi < 4; ++mi)
#pragma unroll
    for (int ni = 0; ni < 4; ++ni)
#pragma unroll
    for (int r = 0; r < 4; ++r) {
        int row = m0 + wr*64 + mi*16 + lk*4 + r;
        int col = n0 + wc*64 + ni*16 + lm;
        U[(size_t)row * 4096 + col] = f2bf(acc[mi][ni][r]);
    }
}

// parity fold: Ae/Ao[bh][2048] from Ys row
//   k==0: yr[0] both ; k in[1,1024): yr[k] +/- yr[2048-k]
//   k in[1024,2047): j=k-1023: yis[j] -/+ yis[2048-j]
//   k==2047: e: yr[1024], o: yis[1024]
__global__ __launch_bounds__(256) void k_par(short* __restrict__ Wb)
{
    __shared__ short row[4096];
    int bh = blockIdx.x, tid = threadIdx.x;
    const short* Ysr = Wb + S_U + (size_t)bh * 4096;
    *(short8*)&row[tid * 16]     = *(const short8*)&Ysr[tid * 16];
    *(short8*)&row[tid * 16 + 8] = *(const short8*)&Ysr[tid * 16 + 8];
    __syncthreads();
    short* Ae = Wb + S_AP + (size_t)bh * 2048;
    short* Ao = Wb + S_AP + (size_t)(4096 + bh) * 2048;
    int k0 = tid * 8;
    short8 ve, vo;
#pragma unroll
    for (int i = 0; i < 8; ++i) {
        int k = k0 + i;
        float e, o;
        if (k == 0) {
            e = o = bf2f(row[0]);
        } else if (k < 1024) {
            float a = bf2f(row[k]), b = bf2f(row[2048 - k]);
            e = a + b; o = a - b;
        } else if (k < 2047) {
            int j = k - 1023;
            float a = bf2f(row[2048 + j]), b = bf2f(row[4096 - j]);
            e = a - b; o = a + b;
        } else {
            e = bf2f(row[1024]);
            o = bf2f(row[2048 + 1024]);
        }
        ve[i] = f2bf(e); vo[i] = f2bf(o);
    }
    *(short8*)&Ae[k0] = ve;
    *(short8*)&Ao[k0] = vo;
}

// inverse: per parity p, y[2tau+p] = Apar_p x B2_p^T, K=2048, BM=256 x BN=128
__global__ __launch_bounds__(512, 1) void k_invB(const float* __restrict__ u,
                                                 const float* __restrict__ Dp,
                                                 short* __restrict__ Wb,
                                                 float* __restrict__ out)
{
    __shared__ short lds_s[57344];   // 112 KB
    int tile = (blockIdx.x & 7) * 32 + (blockIdx.x >> 3);
    const int m0   = (tile >> 4) * 256;     // bh
    const int rest = tile & 15;
    const int p    = rest >> 3;             // parity
    const int n0   = (rest & 7) * 128;      // tau0
    const int tid = threadIdx.x;
    const int wave = tid >> 6, lane = tid & 63;
    const int wm = wave >> 2, wn = wave & 3;
    const int lm = lane & 15, lk = lane >> 4;
    const int srow8 = lane >> 3;
    const int scol  = (lane & 7) * 8;
    constexpr int nt = 32;
    short* lds = lds_s;
    const short* Ag = Wb + S_AP + (size_t)p * 4096 * 2048;   // [4096][2048]
    const short* Bg = Wb + S_T2 + (size_t)p * 1024 * 2048;   // [1024][2048]

    auto stageA = [&](int half, int kt) {
        short* l0 = lds + (size_t)((kt & 1) * 2 + half) * 8192;
#pragma unroll
        for (int q = 0; q < 2; ++q) {
            int chunk = wave * 2 + q;
            int r = chunk * 8 + srow8;
            int c = scol ^ ((r & 7) << 3);
            load_lds16(Ag + (size_t)(m0 + half * 128 + r) * 2048 + kt * 64 + c,
                       l0 + chunk * 512);
        }
    };
    auto stageB = [&](int kt, int slot) {
        short* l0 = lds + 32768 + (size_t)slot * 8192;
#pragma unroll
        for (int q = 0; q < 2; ++q) {
            int chunk = wave * 2 + q;
            int r = chunk * 8 + srow8;
            int c = scol ^ ((r & 7) << 3);
            load_lds16(Bg + (size_t)(n0 + r) * 2048 + kt * 64 + c,
                       l0 + chunk * 512);
        }
    };
    auto rdA = [&](int half, int kt, int mi, int kk) -> short8 {
        int rl = wm * 64 + mi * 16 + lm;
        int c  = (kk * 32 + lk * 8) ^ ((rl & 7) << 3);
        return *(const short8*)(lds + (size_t)((kt & 1) * 2 + half) * 8192 + rl * 64 + c);
    };
    auto rdB = [&](int slot, int ni, int kk) -> short8 {
        int rl = wn * 32 + ni * 16 + lm;
        int c  = (kk * 32 + lk * 8) ^ ((rl & 7) << 3);
        return *(const short8*)(lds + 32768 + (size_t)slot * 8192 + rl * 64 + c);
    };

    f32x4 acc[2][4][2] = {};

    stageA(0, 0);
    stageB(0, 0);
    stageA(1, 0);
    stageA(0, 1);
    stageB(1, 1);
    stageB(2, 2);
    WAIT_VM(6);
    BAR();

    short8 a[4][2], b[2][2];
    int bs = 0;
    for (int t = 0; t < nt; ++t) {
        const bool deep = (t + 3 < nt);
        // ---- P0 ----
#pragma unroll
        for (int mi = 0; mi < 4; ++mi) { a[mi][0] = rdA(0, t, mi, 0); a[mi][1] = rdA(0, t, mi, 1); }
#pragma unroll
        for (int ni = 0; ni < 2; ++ni) { b[ni][0] = rdB(bs, ni, 0); b[ni][1] = rdB(bs, ni, 1); }
        if (t + 1 < nt) stageA(1, t + 1);
        BAR();
        WAIT_LGKM0();
        __builtin_amdgcn_s_setprio(1);
        MFMA16(a, b, acc[0]);
        __builtin_amdgcn_s_setprio(0);
        if (deep) { WAIT_VM(6); } else { WAIT_VM(0); }
        BAR();
        // ---- P1 ----
#pragma unroll
        for (int mi = 0; mi < 4; ++mi) { a[mi][0] = rdA(1, t, mi, 0); a[mi][1] = rdA(1, t, mi, 1); }
        if (t + 2 < nt) stageA(0, t + 2);
        if (t + 3 < nt) stageB(t + 3, bs);
        BAR();
        WAIT_LGKM0();
        __builtin_amdgcn_s_setprio(1);
        MFMA16(a, b, acc[1]);
        __builtin_amdgcn_s_setprio(0);
        if (deep) { WAIT_VM(6); } else { WAIT_VM(0); }
        BAR();
        bs = (bs == 2) ? 0 : bs + 1;
    }

    const int b_  = m0 >> 9;
    const int h00 = m0 & 511;
    float (*T)[132] = (float(*)[132])lds_s;
#pragma unroll
    for (int q = 0; q < 2; ++q) {
        __syncthreads();
#pragma unroll
        for (int mi = 0; mi < 4; ++mi)
#pragma unroll
        for (int ni = 0; ni < 2; ++ni) {
            int tl = wn * 32 + ni * 16 + lm;
            int hl = wm * 64 + mi * 16 + lk * 4;
            *(float4*)&T[tl][hl] = *(float4*)&acc[q][mi][ni];
        }
        __syncthreads();
        int hg = h00 + q * 128 + (tid & 31) * 4;
        float4 dv = *(const float4*)&Dp[hg];
#pragma unroll
        for (int it = 0; it < 8; ++it) {
            int tl = (tid >> 5) + it * 16;
            int tg = 2 * (n0 + tl) + p;
            size_t gidx = ((size_t)b_ * cL + tg) * cH + hg;
            float4 uv = *(const float4*)&u[gidx];
            float4 yv = *(float4*)&T[tl][(tid & 31) * 4];
            yv.x += dv.x * uv.x;
            yv.y += dv.y * uv.y;
            yv.z += dv.z * uv.z;
            yv.w += dv.w * uv.w;
            *(float4*)&out[gidx] = yv;
        }
    }
}

extern "C" void kernel_launch(void* const* d_in, const int* in_sizes, int n_in,
                              void* d_out, int out_size, void* d_ws, size_t ws_size,
                              hipStream_t stream) {
    const float* u    = (const float*)d_in[0];
    const float* w_re = (const float*)d_in[1];
    const float* w_im = (const float*)d_in[2];
    const float* C_re = (const float*)d_in[3];
    const float* C_im = (const float*)d_in[4];
    const float* Dp   = (const float*)d_in[5];
    const float* dt   = (const float*)d_in[6];
    float* out = (float*)d_out;
    short* Wb  = (short*)d_ws;

    hipLaunchKernelGGL(k_tabs,  dim3(4096), dim3(256), 0, stream, Wb);
    hipLaunchKernelGGL(k_trans, dim3(cL / 64, cH / 64, cB), dim3(256), 0, stream, u, Wb);
    hipLaunchKernelGGL(k_kgen,  dim3(cH), dim3(256), 0, stream,
                       w_re, w_im, C_re, C_im, dt, Wb);
    hipLaunchKernelGGL(k_kfg,   dim3(32, 4), dim3(256), 0, stream, Wb);
    hipLaunchKernelGGL(k_fwd8,  dim3(256), dim3(512), 0, stream, Wb);
    hipLaunchKernelGGL(k_par,   dim3(BH), dim3(256), 0, stream, Wb);
    hipLaunchKernelGGL(k_invB,  dim3(256), dim3(512), 0, stream, u, Dp, Wb, out);
}

// Round 13
// 202.941 us; speedup vs baseline: 1.2594x; 1.0477x over previous
//
#include <hip/hip_runtime.h>
#include <hip/hip_bf16.h>
#include <math.h>

// S4DConv via MFMA: B=8, L=2048, H=512, N=64, CH=1
//   k_tabs:  B1'' mirror-paired rows [4p..4p+3]=(cos_p,sin_p,cos_p',sin_p'),
//            p'=(p==0?1024:2048-p); B2 parity tables [2][1024][2048]
//            (k<1024: cos(2pi k t/4096); k=1024: (-1)^tau; k>1024: sin(2pi (k-1024)t/4096))
//   k_trans: A u-rows; k_kgen: A k-rows
//   k_kfg:   KF rows = A_k x B1''^T -> U rows 4096+
//   k_fwd8:  256^2 GEMM; epilogue fuses complex mix + parity fold ->
//            U[bh][0:2048)=Ae, U[bh][2048:4096)=Ao
//   k_invB:  y[2tau+p] = A(e/o) x B2_p^T (K=2048) + fused skip -> out

namespace {
constexpr int cB = 8;
constexpr int cL = 2048;
constexpr int cH = 512;
constexpr int cN = 64;
constexpr int M1 = 4095;
constexpr int M2 = 4096;
constexpr int BH = cB * cH;            // 4096
constexpr int MA = BH + cH;            // 4608

constexpr size_t S0   = 2 * ((size_t)cH * cN * 6);
constexpr size_t S_B1 = S0;                           // [4096][2048] paired
constexpr size_t S_A  = S_B1 + (size_t)4096 * 2048;   // [4608][2048]
constexpr size_t S_T2 = S_A  + (size_t)MA * 2048;     // B2 [2][1024][2048]
constexpr size_t S_U  = S_T2 + (size_t)2048 * 4096;   // [4608][4096]: rows<4096 Ae|Ao; 4096+ KF
}

typedef __attribute__((ext_vector_type(8))) short short8;
typedef __attribute__((ext_vector_type(2))) short sh2;
typedef __attribute__((ext_vector_type(4))) float f32x4;

static __device__ inline short f2bf(float x) {
    __hip_bfloat16 h = __float2bfloat16(x);
    return *reinterpret_cast<short*>(&h);
}
static __device__ inline float bf2f(short s) {
    return __uint_as_float(((unsigned int)(unsigned short)s) << 16);
}
static __device__ __forceinline__ void load_lds16(const short* g, short* l) {
    __builtin_amdgcn_global_load_lds(
        (const __attribute__((address_space(1))) void*)g,
        (__attribute__((address_space(3))) void*)l, 16, 0, 0);
}
#define WAIT_LGKM0() do { asm volatile("s_waitcnt lgkmcnt(0)" ::: "memory"); \
                          __builtin_amdgcn_sched_barrier(0); } while (0)
#define WAIT_VM(n)   do { asm volatile("s_waitcnt vmcnt(" #n ")" ::: "memory"); \
                          __builtin_amdgcn_sched_barrier(0); } while (0)
#define BAR() __builtin_amdgcn_s_barrier()

__global__ __launch_bounds__(256) void k_tabs(short* __restrict__ Wb)
{
    int tid = threadIdx.x;
    if (blockIdx.x < 2048) {              // B1'' rows for DFT j = blockIdx.x
        int j  = blockIdx.x;
        int base = (j < 1024) ? 4 * j : (j == 1024 ? 2 : 4 * (2048 - j) + 2);
        int t0 = tid * 8;
        int p0 = (int)(((long)j * t0) % M1);
        float c, s, cs, ss;
        sincosf((6.283185307179586f / (float)M1) * (float)p0, &s, &c);
        sincosf((6.283185307179586f / (float)M1) * (float)j,  &ss, &cs);
        short8 vc, vs;
#pragma unroll
        for (int i = 0; i < 8; ++i) {
            vc[i] = f2bf(c); vs[i] = f2bf(s);
            float tr = c * cs - s * ss;
            s = c * ss + s * cs;
            c = tr;
        }
        *(short8*)&Wb[S_B1 + (size_t)base       * 2048 + t0] = vc;
        *(short8*)&Wb[S_B1 + (size_t)(base + 1) * 2048 + t0] = vs;
    } else {                              // B2 parity rows
        int r   = blockIdx.x - 2048;
        int p   = r >> 10, tau = r & 1023;
        int t   = 2 * tau + p;
        int k0  = tid * 8;
        float stepang = (6.283185307179586f / (float)M2) * (float)t;
        float cs, ss; sincosf(stepang, &ss, &cs);
        short8 v;
        if (k0 < 1024) {                  // cos chunk (k=0 -> 1 naturally)
            int ph = (k0 * t) & (M2 - 1);
            float c, s; sincosf((6.283185307179586f / (float)M2) * (float)ph, &s, &c);
#pragma unroll
            for (int i = 0; i < 8; ++i) {
                v[i] = f2bf(c);
                float tr = c * cs - s * ss;
                s = c * ss + s * cs;
                c = tr;
            }
        } else {                          // sin chunk, j=k-1024; k==1024 special
            int j0 = k0 - 1024;
            int ph = (j0 * t) & (M2 - 1);
            float c, s; sincosf((6.283185307179586f / (float)M2) * (float)ph, &s, &c);
#pragma unroll
            for (int i = 0; i < 8; ++i) {
                int k = k0 + i;
                v[i] = (k == 1024) ? f2bf((tau & 1) ? -1.f : 1.f) : f2bf(s);
                float tr = c * cs - s * ss;
                s = c * ss + s * cs;
                c = tr;
            }
        }
        *(short8*)&Wb[S_T2 + (size_t)r * 2048 + k0] = v;
    }
}

__global__ __launch_bounds__(256) void k_trans(const float* __restrict__ u,
                                               short* __restrict__ Wb)
{
    __shared__ float tile[64][65];
    int t0 = blockIdx.x * 64;
    int h0 = blockIdx.y * 64;
    int b  = blockIdx.z;
    int cx = threadIdx.x & 63, r0 = threadIdx.x >> 6;
#pragma unroll
    for (int i = 0; i < 16; ++i) {
        int row = r0 + i * 4;
        tile[row][cx] = u[((size_t)b * cL + t0 + row) * cH + h0 + cx];
    }
    __syncthreads();
    short* A = Wb + S_A;
#pragma unroll
    for (int i = 0; i < 16; ++i) {
        int hrow = r0 + i * 4;
        A[(size_t)(b * cH + h0 + hrow) * 2048 + t0 + cx] = f2bf(tile[cx][hrow]);
    }
}

__global__ __launch_bounds__(256) void k_kgen(
    const float* __restrict__ w_re, const float* __restrict__ w_im,
    const float* __restrict__ C_re, const float* __restrict__ C_im,
    const float* __restrict__ dt, short* __restrict__ Wb)
{
    __shared__ float md[cN * 6];
    int h = blockIdx.x, tid = threadIdx.x;
    if (tid < cN) {
        int idx = h * cN + tid;
        double dtv = dt[h];
        double wr = w_re[idx], wi = w_im[idx];
        double ar = wr * dtv, ai = wi * dtv;
        double er = exp(ar);
        double zs, zc; sincos(ai, &zs, &zc);
        double zr = er * zc, zi = er * zs;
        double nr = zr - 1.0, ni = zi;
        double inv = 1.0 / (wr * wr + wi * wi);
        double gr = (nr * wr + ni * wi) * inv;
        double gi = (ni * wr - nr * wi) * inv;
        double cr = C_re[idx], ci = C_im[idx];
        md[tid*6+0] = (float)(cr * gr - ci * gi);
        md[tid*6+1] = (float)(cr * gi + ci * gr);
        md[tid*6+2] = (float)zr; md[tid*6+3] = (float)zi;
        md[tid*6+4] = (float)ar; md[tid*6+5] = (float)ai;
    }
    __syncthreads();
    int t0 = tid * 8;
    float acc[8] = {0.f, 0.f, 0.f, 0.f, 0.f, 0.f, 0.f, 0.f};
    for (int n = 0; n < cN; ++n) {
        float csr = md[n*6+0], csi = md[n*6+1];
        float zr  = md[n*6+2], zi  = md[n*6+3];
        float ar  = md[n*6+4], ai  = md[n*6+5];
        float mag = expf(ar * (float)t0);
        double ph = fmod((double)ai * (double)t0, 6.283185307179586);
        float s, c; sincosf((float)ph, &s, &c);
        float pr = mag * c, pi = mag * s;
#pragma unroll
        for (int i = 0; i < 8; ++i) {
            acc[i] += csr * pr - csi * pi;
            float tr = pr * zr - pi * zi;
            pi = pr * zi + pi * zr;
            pr = tr;
        }
    }
    short8 v;
#pragma unroll
    for (int i = 0; i < 8; ++i) v[i] = f2bf(2.f * acc[i]);
    *reinterpret_cast<short8*>(&Wb[S_A + (size_t)(BH + h) * 2048 + t0]) = v;
}

#define MFMA16(AR, BR, ACC) \
    _Pragma("unroll") for (int kk = 0; kk < 2; ++kk) \
    _Pragma("unroll") for (int ni = 0; ni < 2; ++ni) \
    _Pragma("unroll") for (int mi = 0; mi < 4; ++mi) \
        ACC[mi][ni] = __builtin_amdgcn_mfma_f32_16x16x32_bf16(AR[mi][kk], BR[ni][kk], ACC[mi][ni], 0, 0, 0);

// ------- deep-pipelined 256x256 core (proven r10-r12) -----------------------
__device__ __forceinline__ void gemm8p_core(
    const short* __restrict__ Ag, int lda,
    const short* __restrict__ Bg, int ldb,
    int m0, int n0, int nt, short* lds, f32x4 (&acc)[4][4][2])
{
    const int tid  = threadIdx.x;
    const int wave = tid >> 6, lane = tid & 63;
    const int wm = wave >> 2, wn = wave & 3;
    const int lm = lane & 15, lk = lane >> 4;
    const int srow8 = lane >> 3;
    const int scol  = (lane & 7) * 8;

    auto stage = [&](const short* G, int ldg, int row0, int half, int kt, int sb) {
        short* l0 = lds + sb + (size_t)((kt & 1) * 2 + half) * 8192;
#pragma unroll
        for (int q = 0; q < 2; ++q) {
            int chunk = wave * 2 + q;
            int r = chunk * 8 + srow8;
            int c = scol ^ ((r & 7) << 3);
            load_lds16(G + (size_t)(row0 + half * 128 + r) * ldg + kt * 64 + c,
                       l0 + chunk * 512);
        }
    };
    auto rdA = [&](int qa, int kt, int mi, int kk) -> short8 {
        int rl = wm * 64 + mi * 16 + lm;
        int c  = (kk * 32 + lk * 8) ^ ((rl & 7) << 3);
        return *(const short8*)(lds + (size_t)((kt & 1) * 2 + qa) * 8192 + rl * 64 + c);
    };
    auto rdB = [&](int qb, int kt, int ni, int kk) -> short8 {
        int rl = wn * 32 + ni * 16 + lm;
        int c  = (kk * 32 + lk * 8) ^ ((rl & 7) << 3);
        return *(const short8*)(lds + 32768 + (size_t)((kt & 1) * 2 + qb) * 8192 + rl * 64 + c);
    };

    stage(Ag, lda, m0, 0, 0, 0);
    stage(Bg, ldb, n0, 0, 0, 32768);
    stage(Bg, ldb, n0, 1, 0, 32768);
    stage(Ag, lda, m0, 1, 0, 0);
    stage(Ag, lda, m0, 0, 1, 0);
    stage(Bg, ldb, n0, 0, 1, 32768);
    stage(Bg, ldb, n0, 1, 1, 32768);
    stage(Ag, lda, m0, 1, 1, 0);
    WAIT_VM(12);
    BAR();

    short8 a0[4][2], a1[4][2], b0[2][2], b1[2][2];
    for (int t = 0; t < nt; ++t) {
        const bool st = (t + 2 < nt);
        // ---- P0 ----
#pragma unroll
        for (int mi = 0; mi < 4; ++mi) { a0[mi][0] = rdA(0, t, mi, 0); a0[mi][1] = rdA(0, t, mi, 1); }
#pragma unroll
        for (int ni = 0; ni < 2; ++ni) { b0[ni][0] = rdB(0, t, ni, 0); b0[ni][1] = rdB(0, t, ni, 1); }
        BAR();
        WAIT_LGKM0();
        __builtin_amdgcn_s_setprio(1);
        MFMA16(a0, b0, acc[0]);
        __builtin_amdgcn_s_setprio(0);
        if (st) { WAIT_VM(10); } else { WAIT_VM(0); }
        BAR();
        // ---- P1 ----
#pragma unroll
        for (int ni = 0; ni < 2; ++ni) { b1[ni][0] = rdB(1, t, ni, 0); b1[ni][1] = rdB(1, t, ni, 1); }
        if (st) { stage(Ag, lda, m0, 0, t + 2, 0); stage(Bg, ldb, n0, 0, t + 2, 32768); }
        BAR();
        WAIT_LGKM0();
        __builtin_amdgcn_s_setprio(1);
        MFMA16(a0, b1, acc[1]);
        __builtin_amdgcn_s_setprio(0);
        if (st) { WAIT_VM(12); } else { WAIT_VM(0); }
        BAR();
        // ---- P2 ----
#pragma unroll
        for (int mi = 0; mi < 4; ++mi) { a1[mi][0] = rdA(1, t, mi, 0); a1[mi][1] = rdA(1, t, mi, 1); }
        if (st) stage(Bg, ldb, n0, 1, t + 2, 32768);
        BAR();
        WAIT_LGKM0();
        __builtin_amdgcn_s_setprio(1);
        MFMA16(a1, b1, acc[3]);
        __builtin_amdgcn_s_setprio(0);
        BAR();
        // ---- P3 ----
        if (st) stage(Ag, lda, m0, 1, t + 2, 0);
        __builtin_amdgcn_s_setprio(1);
        MFMA16(a1, b0, acc[2]);
        __builtin_amdgcn_s_setprio(0);
        if (st) { WAIT_VM(12); } else { WAIT_VM(0); }
        BAR();
    }
}

// forward: acc = A_u x B1''^T; epilogue: mix (x KF) + parity fold -> Ae|Ao
__global__ __launch_bounds__(512, 2) void k_fwd8(short* __restrict__ Wb)
{
    __shared__ short lds_s[65536];
    int tile = (blockIdx.x & 7) * 32 + (blockIdx.x >> 3);
    const int m0 = (tile >> 4) * 256, n0 = (tile & 15) * 256;
    const int tid = threadIdx.x;
    const int wave = tid >> 6, lane = tid & 63;
    const int wm = wave >> 2, wn = wave & 3;
    const int lm = lane & 15, lk = lane >> 4;

    f32x4 acc[4][4][2] = {};
    gemm8p_core(Wb + S_A, 2048, Wb + S_B1, 2048, m0, n0, 32, lds_s, acc);

    short* Uw = Wb + S_U;
    const short* KF = Wb + S_U;
    short (*M)[136] = (short(*)[136])lds_s;
    for (int q = 0; q < 4; ++q) {
        __syncthreads();
#pragma unroll
        for (int mi = 0; mi < 4; ++mi)
#pragma unroll
        for (int ni = 0; ni < 2; ++ni)
#pragma unroll
        for (int r = 0; r < 4; ++r)
            M[wm * 64 + mi * 16 + lk * 4 + r][wn * 32 + ni * 16 + lm] =
                f2bf(acc[q][mi][ni][r]);
        __syncthreads();
        const int pq0 = (n0 >> 2) + (q & 1) * 32;   // pair base of quadrant
#pragma unroll
        for (int pass = 0; pass < 4; ++pass) {
            int rl = pass * 32 + (tid >> 4);
            int cp = (tid & 15) * 2;                // pair offset (2 pairs/thr)
            int rowg = m0 + (q >> 1) * 128 + rl;
            int h = rowg & (cH - 1);
            int colg = n0 + (q & 1) * 128 + cp * 4;
            short8 kf8 = *(const short8*)&KF[(size_t)(4096 + h) * 4096 + colg];
            short8 m8  = *(const short8*)&M[rl][cp * 4];
            sh2 vce, vco, vse, vso;
#pragma unroll
            for (int i = 0; i < 2; ++i) {
                float C  = bf2f(m8[4*i]),   S  = bf2f(m8[4*i+1]);
                float C2 = bf2f(m8[4*i+2]), S2 = bf2f(m8[4*i+3]);
                float Ck  = bf2f(kf8[4*i]),   Sk  = bf2f(kf8[4*i+1]);
                float Ck2 = bf2f(kf8[4*i+2]), Sk2 = bf2f(kf8[4*i+3]);
                int p = pq0 + cp + i;
                float scp = (p == 0 ? 1.0f : 2.0f) * (1.0f / (float)M2);
                float scq = 2.0f / (float)M2;
                float yrp = scp * (Ck * C - Sk * S);
                float yip = scp * (Ck * S + Sk * C);
                float yrq = scq * (Ck2 * C2 - Sk2 * S2);
                float yiq = scq * (Ck2 * S2 + Sk2 * C2);
                float ce, co, se, so;
                if (p == 0) { ce = yrp; co = yrp; se = yrq; so = yiq; }
                else { ce = yrp + yrq; co = yrp - yrq; se = yip - yiq; so = yip + yiq; }
                vce[i] = f2bf(ce); vco[i] = f2bf(co);
                vse[i] = f2bf(se); vso[i] = f2bf(so);
            }
            size_t base = (size_t)rowg * 4096;
            int kx = pq0 + cp;
            *(sh2*)&Uw[base + kx]        = vce;   // Ae cos
            *(sh2*)&Uw[base + 1024 + kx] = vse;   // Ae sin
            *(sh2*)&Uw[base + 2048 + kx] = vco;   // Ao cos
            *(sh2*)&Uw[base + 3072 + kx] = vso;   // Ao sin
        }
    }
}

// KF rows: U[4096+h] = A_k x B1''^T
__global__ __launch_bounds__(256, 2) void k_kfg(short* __restrict__ Wb)
{
    __shared__ __align__(16) short As[128][32];
    __shared__ __align__(16) short Bs[128][32];
    const short* A = Wb + S_A;
    const short* B = Wb + S_B1;
    short* U = Wb + S_U;
    const int tid = threadIdx.x;
    const int m0 = 4096 + blockIdx.y * 128, n0 = blockIdx.x * 128;
    const int wave = tid >> 6, lane = tid & 63;
    const int wr = wave >> 1, wc = wave & 1;
    const int lm = lane & 15, lk = lane >> 4;
    const int srow = lane >> 2, scol = (lane & 3) * 8;

    f32x4 acc[4][4] = {};
    for (int k0 = 0; k0 < 2048; k0 += 32) {
        __syncthreads();
        {
            int c0 = wave * 2;
            load_lds16(&A[(size_t)(m0 + c0*16      + srow)*2048 + k0 + scol], &As[c0*16][0]);
            load_lds16(&A[(size_t)(m0 + c0*16 + 16 + srow)*2048 + k0 + scol], &As[c0*16+16][0]);
            load_lds16(&B[(size_t)(n0 + c0*16      + srow)*2048 + k0 + scol], &Bs[c0*16][0]);
            load_lds16(&B[(size_t)(n0 + c0*16 + 16 + srow)*2048 + k0 + scol], &Bs[c0*16+16][0]);
        }
        __syncthreads();
        short8 a[4];
#pragma unroll
        for (int mi = 0; mi < 4; ++mi)
            a[mi] = *(const short8*)&As[wr*64 + mi*16 + lm][lk*8];
#pragma unroll
        for (int ni = 0; ni < 4; ++ni) {
            short8 b = *(const short8*)&Bs[wc*64 + ni*16 + lm][lk*8];
#pragma unroll
            for (int mi = 0; mi < 4; ++mi)
                acc[mi][ni] = __builtin_amdgcn_mfma_f32_16x16x32_bf16(a[mi], b, acc[mi][ni], 0, 0, 0);
        }
    }
#pragma unroll
    for (int mi = 0; mi < 4; ++mi)
#pragma unroll
    for (int ni = 0; ni < 4; ++ni)
#pragma unroll
    for (int r = 0; r < 4; ++r) {
        int row = m0 + wr*64 + mi*16 + lk*4 + r;
        int col = n0 + wc*64 + ni*16 + lm;
        U[(size_t)row * 4096 + col] = f2bf(acc[mi][ni][r]);
    }
}

// inverse: per parity p, y[2tau+p] = A(e/o) x B2_p^T, K=2048, BM=256 x BN=128
__global__ __launch_bounds__(512, 1) void k_invB(const float* __restrict__ u,
                                                 const float* __restrict__ Dp,
                                                 short* __restrict__ Wb,
                                                 float* __restrict__ out)
{
    __shared__ short lds_s[57344];   // 112 KB
    int tile = (blockIdx.x & 7) * 32 + (blockIdx.x >> 3);
    const int m0   = (tile >> 4) * 256;     // bh
    const int rest = tile & 15;
    const int p    = rest >> 3;             // parity
    const int n0   = (rest & 7) * 128;      // tau0
    const int tid = threadIdx.x;
    const int wave = tid >> 6, lane = tid & 63;
    const int wm = wave >> 2, wn = wave & 3;
    const int lm = lane & 15, lk = lane >> 4;
    const int srow8 = lane >> 3;
    const int scol  = (lane & 7) * 8;
    constexpr int nt = 32;
    short* lds = lds_s;
    const short* Ag = Wb + S_U + (size_t)p * 2048;           // Ae|Ao in U rows, lda 4096
    const short* Bg = Wb + S_T2 + (size_t)p * 1024 * 2048;   // [1024][2048]

    auto stageA = [&](int half, int kt) {
        short* l0 = lds + (size_t)((kt & 1) * 2 + half) * 8192;
#pragma unroll
        for (int q = 0; q < 2; ++q) {
            int chunk = wave * 2 + q;
            int r = chunk * 8 + srow8;
            int c = scol ^ ((r & 7) << 3);
            load_lds16(Ag + (size_t)(m0 + half * 128 + r) * 4096 + kt * 64 + c,
                       l0 + chunk * 512);
        }
    };
    auto stageB = [&](int kt, int slot) {
        short* l0 = lds + 32768 + (size_t)slot * 8192;
#pragma unroll
        for (int q = 0; q < 2; ++q) {
            int chunk = wave * 2 + q;
            int r = chunk * 8 + srow8;
            int c = scol ^ ((r & 7) << 3);
            load_lds16(Bg + (size_t)(n0 + r) * 2048 + kt * 64 + c,
                       l0 + chunk * 512);
        }
    };
    auto rdA = [&](int half, int kt, int mi, int kk) -> short8 {
        int rl = wm * 64 + mi * 16 + lm;
        int c  = (kk * 32 + lk * 8) ^ ((rl & 7) << 3);
        return *(const short8*)(lds + (size_t)((kt & 1) * 2 + half) * 8192 + rl * 64 + c);
    };
    auto rdB = [&](int slot, int ni, int kk) -> short8 {
        int rl = wn * 32 + ni * 16 + lm;
        int c  = (kk * 32 + lk * 8) ^ ((rl & 7) << 3);
        return *(const short8*)(lds + 32768 + (size_t)slot * 8192 + rl * 64 + c);
    };

    f32x4 acc[2][4][2] = {};

    stageA(0, 0);
    stageB(0, 0);
    stageA(1, 0);
    stageA(0, 1);
    stageB(1, 1);
    stageB(2, 2);
    WAIT_VM(6);
    BAR();

    short8 a[4][2], b[2][2];
    int bs = 0;
    for (int t = 0; t < nt; ++t) {
        const bool deep = (t + 3 < nt);
        // ---- P0 ----
#pragma unroll
        for (int mi = 0; mi < 4; ++mi) { a[mi][0] = rdA(0, t, mi, 0); a[mi][1] = rdA(0, t, mi, 1); }
#pragma unroll
        for (int ni = 0; ni < 2; ++ni) { b[ni][0] = rdB(bs, ni, 0); b[ni][1] = rdB(bs, ni, 1); }
        if (t + 1 < nt) stageA(1, t + 1);
        BAR();
        WAIT_LGKM0();
        __builtin_amdgcn_s_setprio(1);
        MFMA16(a, b, acc[0]);
        __builtin_amdgcn_s_setprio(0);
        if (deep) { WAIT_VM(6); } else { WAIT_VM(0); }
        BAR();
        // ---- P1 ----
#pragma unroll
        for (int mi = 0; mi < 4; ++mi) { a[mi][0] = rdA(1, t, mi, 0); a[mi][1] = rdA(1, t, mi, 1); }
        if (t + 2 < nt) stageA(0, t + 2);
        if (t + 3 < nt) stageB(t + 3, bs);
        BAR();
        WAIT_LGKM0();
        __builtin_amdgcn_s_setprio(1);
        MFMA16(a, b, acc[1]);
        __builtin_amdgcn_s_setprio(0);
        if (deep) { WAIT_VM(6); } else { WAIT_VM(0); }
        BAR();
        bs = (bs == 2) ? 0 : bs + 1;
    }

    const int b_  = m0 >> 9;
    const int h00 = m0 & 511;
    float (*T)[132] = (float(*)[132])lds_s;
#pragma unroll
    for (int q = 0; q < 2; ++q) {
        __syncthreads();
#pragma unroll
        for (int mi = 0; mi < 4; ++mi)
#pragma unroll
        for (int ni = 0; ni < 2; ++ni) {
            int tl = wn * 32 + ni * 16 + lm;
            int hl = wm * 64 + mi * 16 + lk * 4;
            *(float4*)&T[tl][hl] = *(float4*)&acc[q][mi][ni];
        }
        __syncthreads();
        int hg = h00 + q * 128 + (tid & 31) * 4;
        float4 dv = *(const float4*)&Dp[hg];
#pragma unroll
        for (int it = 0; it < 8; ++it) {
            int tl = (tid >> 5) + it * 16;
            int tg = 2 * (n0 + tl) + p;
            size_t gidx = ((size_t)b_ * cL + tg) * cH + hg;
            float4 uv = *(const float4*)&u[gidx];
            float4 yv = *(float4*)&T[tl][(tid & 31) * 4];
            yv.x += dv.x * uv.x;
            yv.y += dv.y * uv.y;
            yv.z += dv.z * uv.z;
            yv.w += dv.w * uv.w;
            *(float4*)&out[gidx] = yv;
        }
    }
}

extern "C" void kernel_launch(void* const* d_in, const int* in_sizes, int n_in,
                              void* d_out, int out_size, void* d_ws, size_t ws_size,
                              hipStream_t stream) {
    const float* u    = (const float*)d_in[0];
    const float* w_re = (const float*)d_in[1];
    const float* w_im = (const float*)d_in[2];
    const float* C_re = (const float*)d_in[3];
    const float* C_im = (const float*)d_in[4];
    const float* Dp   = (const float*)d_in[5];
    const float* dt   = (const float*)d_in[6];
    float* out = (float*)d_out;
    short* Wb  = (short*)d_ws;

    hipLaunchKernelGGL(k_tabs,  dim3(4096), dim3(256), 0, stream, Wb);
    hipLaunchKernelGGL(k_trans, dim3(cL / 64, cH / 64, cB), dim3(256), 0, stream, u, Wb);
    hipLaunchKernelGGL(k_kgen,  dim3(cH), dim3(256), 0, stream,
                       w_re, w_im, C_re, C_im, dt, Wb);
    hipLaunchKernelGGL(k_kfg,   dim3(32, 4), dim3(256), 0, stream, Wb);
    hipLaunchKernelGGL(k_fwd8,  dim3(256), dim3(512), 0, stream, Wb);
    hipLaunchKernelGGL(k_invB,  dim3(256), dim3(512), 0, stream, u, Dp, Wb, out);
}

// Round 14
// 199.205 us; speedup vs baseline: 1.2831x; 1.0188x over previous
//
#include <hip/hip_runtime.h>
#include <hip/hip_bf16.h>
#include <math.h>

// S4DConv via MFMA: B=8, L=2048, H=512, N=64, CH=1
//   r14: fragment READ-AHEAD in both GEMM cores — ds_reads issued one phase
//   early (under previous MFMA cluster), counted lgkmcnt(n) before each MFMA.
//   Ledger re-derived; vmcnt: fwd8 {P0:8,P2:10,P3:10}, invB {VM(4),VM(4)}.

namespace {
constexpr int cB = 8;
constexpr int cL = 2048;
constexpr int cH = 512;
constexpr int cN = 64;
constexpr int M1 = 4095;
constexpr int M2 = 4096;
constexpr int BH = cB * cH;            // 4096
constexpr int MA = BH + cH;            // 4608

constexpr size_t S0   = 2 * ((size_t)cH * cN * 6);
constexpr size_t S_B1 = S0;                           // [4096][2048] paired
constexpr size_t S_A  = S_B1 + (size_t)4096 * 2048;   // [4608][2048]
constexpr size_t S_T2 = S_A  + (size_t)MA * 2048;     // B2 [2][1024][2048]
constexpr size_t S_U  = S_T2 + (size_t)2048 * 4096;   // [4608][4096]: rows<4096 Ae|Ao; 4096+ KF
}

typedef __attribute__((ext_vector_type(8))) short short8;
typedef __attribute__((ext_vector_type(2))) short sh2;
typedef __attribute__((ext_vector_type(4))) float f32x4;

static __device__ inline short f2bf(float x) {
    __hip_bfloat16 h = __float2bfloat16(x);
    return *reinterpret_cast<short*>(&h);
}
static __device__ inline float bf2f(short s) {
    return __uint_as_float(((unsigned int)(unsigned short)s) << 16);
}
static __device__ __forceinline__ void load_lds16(const short* g, short* l) {
    __builtin_amdgcn_global_load_lds(
        (const __attribute__((address_space(1))) void*)g,
        (__attribute__((address_space(3))) void*)l, 16, 0, 0);
}
#define WAIT_LGKM0() do { asm volatile("s_waitcnt lgkmcnt(0)" ::: "memory"); \
                          __builtin_amdgcn_sched_barrier(0); } while (0)
#define WAIT_LGKM(n) do { asm volatile("s_waitcnt lgkmcnt(" #n ")" ::: "memory"); \
                          __builtin_amdgcn_sched_barrier(0); } while (0)
#define WAIT_VM(n)   do { asm volatile("s_waitcnt vmcnt(" #n ")" ::: "memory"); \
                          __builtin_amdgcn_sched_barrier(0); } while (0)
#define BAR() __builtin_amdgcn_s_barrier()

__global__ __launch_bounds__(256) void k_tabs(short* __restrict__ Wb)
{
    int tid = threadIdx.x;
    if (blockIdx.x < 2048) {              // B1'' rows for DFT j = blockIdx.x
        int j  = blockIdx.x;
        int base = (j < 1024) ? 4 * j : (j == 1024 ? 2 : 4 * (2048 - j) + 2);
        int t0 = tid * 8;
        int p0 = (int)(((long)j * t0) % M1);
        float c, s, cs, ss;
        sincosf((6.283185307179586f / (float)M1) * (float)p0, &s, &c);
        sincosf((6.283185307179586f / (float)M1) * (float)j,  &ss, &cs);
        short8 vc, vs;
#pragma unroll
        for (int i = 0; i < 8; ++i) {
            vc[i] = f2bf(c); vs[i] = f2bf(s);
            float tr = c * cs - s * ss;
            s = c * ss + s * cs;
            c = tr;
        }
        *(short8*)&Wb[S_B1 + (size_t)base       * 2048 + t0] = vc;
        *(short8*)&Wb[S_B1 + (size_t)(base + 1) * 2048 + t0] = vs;
    } else {                              // B2 parity rows
        int r   = blockIdx.x - 2048;
        int p   = r >> 10, tau = r & 1023;
        int t   = 2 * tau + p;
        int k0  = tid * 8;
        float stepang = (6.283185307179586f / (float)M2) * (float)t;
        float cs, ss; sincosf(stepang, &ss, &cs);
        short8 v;
        if (k0 < 1024) {                  // cos chunk
            int ph = (k0 * t) & (M2 - 1);
            float c, s; sincosf((6.283185307179586f / (float)M2) * (float)ph, &s, &c);
#pragma unroll
            for (int i = 0; i < 8; ++i) {
                v[i] = f2bf(c);
                float tr = c * cs - s * ss;
                s = c * ss + s * cs;
                c = tr;
            }
        } else {                          // sin chunk, j=k-1024; k==1024 special
            int j0 = k0 - 1024;
            int ph = (j0 * t) & (M2 - 1);
            float c, s; sincosf((6.283185307179586f / (float)M2) * (float)ph, &s, &c);
#pragma unroll
            for (int i = 0; i < 8; ++i) {
                int k = k0 + i;
                v[i] = (k == 1024) ? f2bf((tau & 1) ? -1.f : 1.f) : f2bf(s);
                float tr = c * cs - s * ss;
                s = c * ss + s * cs;
                c = tr;
            }
        }
        *(short8*)&Wb[S_T2 + (size_t)r * 2048 + k0] = v;
    }
}

__global__ __launch_bounds__(256) void k_trans(const float* __restrict__ u,
                                               short* __restrict__ Wb)
{
    __shared__ float tile[64][65];
    int t0 = blockIdx.x * 64;
    int h0 = blockIdx.y * 64;
    int b  = blockIdx.z;
    int cx = threadIdx.x & 63, r0 = threadIdx.x >> 6;
#pragma unroll
    for (int i = 0; i < 16; ++i) {
        int row = r0 + i * 4;
        tile[row][cx] = u[((size_t)b * cL + t0 + row) * cH + h0 + cx];
    }
    __syncthreads();
    short* A = Wb + S_A;
#pragma unroll
    for (int i = 0; i < 16; ++i) {
        int hrow = r0 + i * 4;
        A[(size_t)(b * cH + h0 + hrow) * 2048 + t0 + cx] = f2bf(tile[cx][hrow]);
    }
}

__global__ __launch_bounds__(256) void k_kgen(
    const float* __restrict__ w_re, const float* __restrict__ w_im,
    const float* __restrict__ C_re, const float* __restrict__ C_im,
    const float* __restrict__ dt, short* __restrict__ Wb)
{
    __shared__ float md[cN * 6];
    int h = blockIdx.x, tid = threadIdx.x;
    if (tid < cN) {
        int idx = h * cN + tid;
        double dtv = dt[h];
        double wr = w_re[idx], wi = w_im[idx];
        double ar = wr * dtv, ai = wi * dtv;
        double er = exp(ar);
        double zs, zc; sincos(ai, &zs, &zc);
        double zr = er * zc, zi = er * zs;
        double nr = zr - 1.0, ni = zi;
        double inv = 1.0 / (wr * wr + wi * wi);
        double gr = (nr * wr + ni * wi) * inv;
        double gi = (ni * wr - nr * wi) * inv;
        double cr = C_re[idx], ci = C_im[idx];
        md[tid*6+0] = (float)(cr * gr - ci * gi);
        md[tid*6+1] = (float)(cr * gi + ci * gr);
        md[tid*6+2] = (float)zr; md[tid*6+3] = (float)zi;
        md[tid*6+4] = (float)ar; md[tid*6+5] = (float)ai;
    }
    __syncthreads();
    int t0 = tid * 8;
    float acc[8] = {0.f, 0.f, 0.f, 0.f, 0.f, 0.f, 0.f, 0.f};
    for (int n = 0; n < cN; ++n) {
        float csr = md[n*6+0], csi = md[n*6+1];
        float zr  = md[n*6+2], zi  = md[n*6+3];
        float ar  = md[n*6+4], ai  = md[n*6+5];
        float mag = expf(ar * (float)t0);
        double ph = fmod((double)ai * (double)t0, 6.283185307179586);
        float s, c; sincosf((float)ph, &s, &c);
        float pr = mag * c, pi = mag * s;
#pragma unroll
        for (int i = 0; i < 8; ++i) {
            acc[i] += csr * pr - csi * pi;
            float tr = pr * zr - pi * zi;
            pi = pr * zi + pi * zr;
            pr = tr;
        }
    }
    short8 v;
#pragma unroll
    for (int i = 0; i < 8; ++i) v[i] = f2bf(2.f * acc[i]);
    *reinterpret_cast<short8*>(&Wb[S_A + (size_t)(BH + h) * 2048 + t0]) = v;
}

#define MFMA16(AR, BR, ACC) \
    _Pragma("unroll") for (int kk = 0; kk < 2; ++kk) \
    _Pragma("unroll") for (int ni = 0; ni < 2; ++ni) \
    _Pragma("unroll") for (int mi = 0; mi < 4; ++mi) \
        ACC[mi][ni] = __builtin_amdgcn_mfma_f32_16x16x32_bf16(AR[mi][kk], BR[ni][kk], ACC[mi][ni], 0, 0, 0);

// ------- 256x256 core with fragment read-ahead ------------------------------
// Reads for phase p+1 issue during phase p (under p's MFMA); counted lgkmcnt.
// vmcnt ledger (verified by simulation from prologue):
//   endP0: VM(8)  retires A1(t)      (needed: P1 reads a1(t))
//   endP2: VM(10) retires A0,B0(t+1) (needed: P3 reads a0/b0(t+1))
//   endP3: VM(10) retires B1(t+1)    (needed: P0(t+1) reads b1(t+1))
__device__ __forceinline__ void gemm8p_core(
    const short* __restrict__ Ag, int lda,
    const short* __restrict__ Bg, int ldb,
    int m0, int n0, int nt, short* lds, f32x4 (&acc)[4][4][2])
{
    const int tid  = threadIdx.x;
    const int wave = tid >> 6, lane = tid & 63;
    const int wm = wave >> 2, wn = wave & 3;
    const int lm = lane & 15, lk = lane >> 4;
    const int srow8 = lane >> 3;
    const int scol  = (lane & 7) * 8;

    auto stage = [&](const short* G, int ldg, int row0, int half, int kt, int sb) {
        short* l0 = lds + sb + (size_t)((kt & 1) * 2 + half) * 8192;
#pragma unroll
        for (int q = 0; q < 2; ++q) {
            int chunk = wave * 2 + q;
            int r = chunk * 8 + srow8;
            int c = scol ^ ((r & 7) << 3);
            load_lds16(G + (size_t)(row0 + half * 128 + r) * ldg + kt * 64 + c,
                       l0 + chunk * 512);
        }
    };
    auto rdA = [&](int qa, int kt, int mi, int kk) -> short8 {
        int rl = wm * 64 + mi * 16 + lm;
        int c  = (kk * 32 + lk * 8) ^ ((rl & 7) << 3);
        return *(const short8*)(lds + (size_t)((kt & 1) * 2 + qa) * 8192 + rl * 64 + c);
    };
    auto rdB = [&](int qb, int kt, int ni, int kk) -> short8 {
        int rl = wn * 32 + ni * 16 + lm;
        int c  = (kk * 32 + lk * 8) ^ ((rl & 7) << 3);
        return *(const short8*)(lds + 32768 + (size_t)((kt & 1) * 2 + qb) * 8192 + rl * 64 + c);
    };

    // prologue: tiles 0,1 fully staged (16 loads)
    stage(Ag, lda, m0, 0, 0, 0);
    stage(Bg, ldb, n0, 0, 0, 32768);
    stage(Bg, ldb, n0, 1, 0, 32768);
    stage(Ag, lda, m0, 1, 0, 0);
    stage(Ag, lda, m0, 0, 1, 0);
    stage(Bg, ldb, n0, 0, 1, 32768);
    stage(Bg, ldb, n0, 1, 1, 32768);
    stage(Ag, lda, m0, 1, 1, 0);
    WAIT_VM(12);                 // A0(0),B0(0) landed
    BAR();

    short8 a0[4][2], a1[4][2], b0[2][2], b1[2][2], b0n[2][2];
#pragma unroll
    for (int mi = 0; mi < 4; ++mi) { a0[mi][0] = rdA(0, 0, mi, 0); a0[mi][1] = rdA(0, 0, mi, 1); }
#pragma unroll
    for (int ni = 0; ni < 2; ++ni) { b0[ni][0] = rdB(0, 0, ni, 0); b0[ni][1] = rdB(0, 0, ni, 1); }
    WAIT_VM(10);                 // B1(0) landed
    BAR();

    for (int t = 0; t < nt; ++t) {
        const bool st = (t + 2 < nt);
        const bool rd = (t + 1 < nt);
        // ---- P0: rd-ahead b1(t); MFMA Q00(a0,b0) ----
#pragma unroll
        for (int ni = 0; ni < 2; ++ni) { b1[ni][0] = rdB(1, t, ni, 0); b1[ni][1] = rdB(1, t, ni, 1); }
        BAR();
        WAIT_LGKM(4);
        __builtin_amdgcn_s_setprio(1);
        MFMA16(a0, b0, acc[0]);
        __builtin_amdgcn_s_setprio(0);
        if (rd) { WAIT_VM(8); } else { WAIT_VM(0); }
        BAR();
        // ---- P1: rd-ahead a1(t); stage A0,B0(t+2); MFMA Q01(a0,b1) ----
#pragma unroll
        for (int mi = 0; mi < 4; ++mi) { a1[mi][0] = rdA(1, t, mi, 0); a1[mi][1] = rdA(1, t, mi, 1); }
        if (st) { stage(Ag, lda, m0, 0, t + 2, 0); stage(Bg, ldb, n0, 0, t + 2, 32768); }
        BAR();
        WAIT_LGKM(8);
        __builtin_amdgcn_s_setprio(1);
        MFMA16(a0, b1, acc[1]);
        __builtin_amdgcn_s_setprio(0);
        BAR();
        // ---- P2: stage B1(t+2); MFMA Q11(a1,b1) ----
        if (st) stage(Bg, ldb, n0, 1, t + 2, 32768);
        BAR();
        WAIT_LGKM0();
        __builtin_amdgcn_s_setprio(1);
        MFMA16(a1, b1, acc[3]);
        __builtin_amdgcn_s_setprio(0);
        if (st) { WAIT_VM(10); } else { WAIT_VM(0); }
        BAR();
        // ---- P3: rd-ahead a0,b0n(t+1); stage A1(t+2); MFMA Q10(a1,b0) ----
        if (rd) {
#pragma unroll
            for (int mi = 0; mi < 4; ++mi) { a0[mi][0] = rdA(0, t + 1, mi, 0); a0[mi][1] = rdA(0, t + 1, mi, 1); }
#pragma unroll
            for (int ni = 0; ni < 2; ++ni) { b0n[ni][0] = rdB(0, t + 1, ni, 0); b0n[ni][1] = rdB(0, t + 1, ni, 1); }
        }
        if (st) stage(Ag, lda, m0, 1, t + 2, 0);
        BAR();
        __builtin_amdgcn_s_setprio(1);
        MFMA16(a1, b0, acc[2]);
        __builtin_amdgcn_s_setprio(0);
        if (rd) {
#pragma unroll
            for (int ni = 0; ni < 2; ++ni) { b0[ni][0] = b0n[ni][0]; b0[ni][1] = b0n[ni][1]; }
            WAIT_VM(10);
        } else { WAIT_VM(0); }
        BAR();
    }
}

// forward: acc = A_u x B1''^T; epilogue: mix (x KF) + parity fold -> Ae|Ao
__global__ __launch_bounds__(512, 2) void k_fwd8(short* __restrict__ Wb)
{
    __shared__ short lds_s[65536];
    int tile = (blockIdx.x & 7) * 32 + (blockIdx.x >> 3);
    const int m0 = (tile >> 4) * 256, n0 = (tile & 15) * 256;
    const int tid = threadIdx.x;
    const int wave = tid >> 6, lane = tid & 63;
    const int wm = wave >> 2, wn = wave & 3;
    const int lm = lane & 15, lk = lane >> 4;

    f32x4 acc[4][4][2] = {};
    gemm8p_core(Wb + S_A, 2048, Wb + S_B1, 2048, m0, n0, 32, lds_s, acc);

    short* Uw = Wb + S_U;
    const short* KF = Wb + S_U;
    short (*M)[136] = (short(*)[136])lds_s;
    for (int q = 0; q < 4; ++q) {
        __syncthreads();
#pragma unroll
        for (int mi = 0; mi < 4; ++mi)
#pragma unroll
        for (int ni = 0; ni < 2; ++ni)
#pragma unroll
        for (int r = 0; r < 4; ++r)
            M[wm * 64 + mi * 16 + lk * 4 + r][wn * 32 + ni * 16 + lm] =
                f2bf(acc[q][mi][ni][r]);
        __syncthreads();
        const int pq0 = (n0 >> 2) + (q & 1) * 32;
#pragma unroll
        for (int pass = 0; pass < 4; ++pass) {
            int rl = pass * 32 + (tid >> 4);
            int cp = (tid & 15) * 2;
            int rowg = m0 + (q >> 1) * 128 + rl;
            int h = rowg & (cH - 1);
            int colg = n0 + (q & 1) * 128 + cp * 4;
            short8 kf8 = *(const short8*)&KF[(size_t)(4096 + h) * 4096 + colg];
            short8 m8  = *(const short8*)&M[rl][cp * 4];
            sh2 vce, vco, vse, vso;
#pragma unroll
            for (int i = 0; i < 2; ++i) {
                float C  = bf2f(m8[4*i]),   S  = bf2f(m8[4*i+1]);
                float C2 = bf2f(m8[4*i+2]), S2 = bf2f(m8[4*i+3]);
                float Ck  = bf2f(kf8[4*i]),   Sk  = bf2f(kf8[4*i+1]);
                float Ck2 = bf2f(kf8[4*i+2]), Sk2 = bf2f(kf8[4*i+3]);
                int p = pq0 + cp + i;
                float scp = (p == 0 ? 1.0f : 2.0f) * (1.0f / (float)M2);
                float scq = 2.0f / (float)M2;
                float yrp = scp * (Ck * C - Sk * S);
                float yip = scp * (Ck * S + Sk * C);
                float yrq = scq * (Ck2 * C2 - Sk2 * S2);
                float yiq = scq * (Ck2 * S2 + Sk2 * C2);
                float ce, co, se, so;
                if (p == 0) { ce = yrp; co = yrp; se = yrq; so = yiq; }
                else { ce = yrp + yrq; co = yrp - yrq; se = yip - yiq; so = yip + yiq; }
                vce[i] = f2bf(ce); vco[i] = f2bf(co);
                vse[i] = f2bf(se); vso[i] = f2bf(so);
            }
            size_t base = (size_t)rowg * 4096;
            int kx = pq0 + cp;
            *(sh2*)&Uw[base + kx]        = vce;
            *(sh2*)&Uw[base + 1024 + kx] = vse;
            *(sh2*)&Uw[base + 2048 + kx] = vco;
            *(sh2*)&Uw[base + 3072 + kx] = vso;
        }
    }
}

// KF rows: U[4096+h] = A_k x B1''^T
__global__ __launch_bounds__(256, 2) void k_kfg(short* __restrict__ Wb)
{
    __shared__ __align__(16) short As[128][32];
    __shared__ __align__(16) short Bs[128][32];
    const short* A = Wb + S_A;
    const short* B = Wb + S_B1;
    short* U = Wb + S_U;
    const int tid = threadIdx.x;
    const int m0 = 4096 + blockIdx.y * 128, n0 = blockIdx.x * 128;
    const int wave = tid >> 6, lane = tid & 63;
    const int wr = wave >> 1, wc = wave & 1;
    const int lm = lane & 15, lk = lane >> 4;
    const int srow = lane >> 2, scol = (lane & 3) * 8;

    f32x4 acc[4][4] = {};
    for (int k0 = 0; k0 < 2048; k0 += 32) {
        __syncthreads();
        {
            int c0 = wave * 2;
            load_lds16(&A[(size_t)(m0 + c0*16      + srow)*2048 + k0 + scol], &As[c0*16][0]);
            load_lds16(&A[(size_t)(m0 + c0*16 + 16 + srow)*2048 + k0 + scol], &As[c0*16+16][0]);
            load_lds16(&B[(size_t)(n0 + c0*16      + srow)*2048 + k0 + scol], &Bs[c0*16][0]);
            load_lds16(&B[(size_t)(n0 + c0*16 + 16 + srow)*2048 + k0 + scol], &Bs[c0*16+16][0]);
        }
        __syncthreads();
        short8 a[4];
#pragma unroll
        for (int mi = 0; mi < 4; ++mi)
            a[mi] = *(const short8*)&As[wr*64 + mi*16 + lm][lk*8];
#pragma unroll
        for (int ni = 0; ni < 4; ++ni) {
            short8 b = *(const short8*)&Bs[wc*64 + ni*16 + lm][lk*8];
#pragma unroll
            for (int mi = 0; mi < 4; ++mi)
                acc[mi][ni] = __builtin_amdgcn_mfma_f32_16x16x32_bf16(a[mi], b, acc[mi][ni], 0, 0, 0);
        }
    }
#pragma unroll
    for (int mi = 0; mi < 4; ++mi)
#pragma unroll
    for (int ni = 0; ni < 4; ++ni)
#pragma unroll
    for (int r = 0; r < 4; ++r) {
        int row = m0 + wr*64 + mi*16 + lk*4 + r;
        int col = n0 + wc*64 + ni*16 + lm;
        U[(size_t)row * 4096 + col] = f2bf(acc[mi][ni][r]);
    }
}

// inverse: per parity p, y[2tau+p] = A(e/o) x B2_p^T, K=2048, BM=256 x BN=128
// read-ahead: P0 reads a1(t); P1 reads a0(t+1)+bn(t+1). VM(4) at both ends.
__global__ __launch_bounds__(512, 1) void k_invB(const float* __restrict__ u,
                                                 const float* __restrict__ Dp,
                                                 short* __restrict__ Wb,
                                                 float* __restrict__ out)
{
    __shared__ short lds_s[57344];   // 112 KB
    int tile = (blockIdx.x & 7) * 32 + (blockIdx.x >> 3);
    const int m0   = (tile >> 4) * 256;     // bh
    const int rest = tile & 15;
    const int p    = rest >> 3;             // parity
    const int n0   = (rest & 7) * 128;      // tau0
    const int tid = threadIdx.x;
    const int wave = tid >> 6, lane = tid & 63;
    const int wm = wave >> 2, wn = wave & 3;
    const int lm = lane & 15, lk = lane >> 4;
    const int srow8 = lane >> 3;
    const int scol  = (lane & 7) * 8;
    constexpr int nt = 32;
    short* lds = lds_s;
    const short* Ag = Wb + S_U + (size_t)p * 2048;           // Ae|Ao, lda 4096
    const short* Bg = Wb + S_T2 + (size_t)p * 1024 * 2048;   // [1024][2048]

    auto stageA = [&](int half, int kt) {
        short* l0 = lds + (size_t)((kt & 1) * 2 + half) * 8192;
#pragma unroll
        for (int q = 0; q < 2; ++q) {
            int chunk = wave * 2 + q;
            int r = chunk * 8 + srow8;
            int c = scol ^ ((r & 7) << 3);
            load_lds16(Ag + (size_t)(m0 + half * 128 + r) * 4096 + kt * 64 + c,
                       l0 + chunk * 512);
        }
    };
    auto stageB = [&](int kt, int slot) {
        short* l0 = lds + 32768 + (size_t)slot * 8192;
#pragma unroll
        for (int q = 0; q < 2; ++q) {
            int chunk = wave * 2 + q;
            int r = chunk * 8 + srow8;
            int c = scol ^ ((r & 7) << 3);
            load_lds16(Bg + (size_t)(n0 + r) * 2048 + kt * 64 + c,
                       l0 + chunk * 512);
        }
    };
    auto rdA = [&](int half, int kt, int mi, int kk) -> short8 {
        int rl = wm * 64 + mi * 16 + lm;
        int c  = (kk * 32 + lk * 8) ^ ((rl & 7) << 3);
        return *(const short8*)(lds + (size_t)((kt & 1) * 2 + half) * 8192 + rl * 64 + c);
    };
    auto rdB = [&](int slot, int ni, int kk) -> short8 {
        int rl = wn * 32 + ni * 16 + lm;
        int c  = (kk * 32 + lk * 8) ^ ((rl & 7) << 3);
        return *(const short8*)(lds + 32768 + (size_t)slot * 8192 + rl * 64 + c);
    };

    f32x4 acc[2][4][2] = {};

    // prologue: A0(0),B(0),A1(0),A0(1),B(1),B(2)  [12 loads]
    stageA(0, 0);
    stageB(0, 0);
    stageA(1, 0);
    stageA(0, 1);
    stageB(1, 1);
    stageB(2, 2);
    WAIT_VM(8);                  // A0(0),B(0) landed
    BAR();
    short8 a0[4][2], a1[4][2], b[2][2], bn[2][2];
#pragma unroll
    for (int mi = 0; mi < 4; ++mi) { a0[mi][0] = rdA(0, 0, mi, 0); a0[mi][1] = rdA(0, 0, mi, 1); }
#pragma unroll
    for (int ni = 0; ni < 2; ++ni) { b[ni][0] = rdB(0, ni, 0); b[ni][1] = rdB(0, ni, 1); }
    WAIT_VM(4);                  // A1(0) landed
    BAR();

    int bs = 0;
    for (int t = 0; t < nt; ++t) {
        const bool r1 = (t + 1 < nt);
        const bool s2 = (t + 2 < nt);
        const bool s3 = (t + 3 < nt);
        const bool tail = (t >= nt - 3);
        const int bs2 = (bs == 2) ? 0 : bs + 1;
        // ---- P0: rd-ahead a1(t); stage A1(t+1); MFMA(a0,b) ----
#pragma unroll
        for (int mi = 0; mi < 4; ++mi) { a1[mi][0] = rdA(1, t, mi, 0); a1[mi][1] = rdA(1, t, mi, 1); }
        if (r1) stageA(1, t + 1);
        BAR();
        WAIT_LGKM(8);
        __builtin_amdgcn_s_setprio(1);
        MFMA16(a0, b, acc[0]);
        __builtin_amdgcn_s_setprio(0);
        if (tail) { WAIT_VM(0); } else { WAIT_VM(4); }
        BAR();
        // ---- P1: rd-ahead a0(t+1),bn(t+1); stage A0(t+2),B(t+3); MFMA(a1,b) ----
        if (r1) {
#pragma unroll
            for (int mi = 0; mi < 4; ++mi) { a0[mi][0] = rdA(0, t + 1, mi, 0); a0[mi][1] = rdA(0, t + 1, mi, 1); }
#pragma unroll
            for (int ni = 0; ni < 2; ++ni) { bn[ni][0] = rdB(bs2, ni, 0); bn[ni][1] = rdB(bs2, ni, 1); }
        }
        if (s2) stageA(0, t + 2);
        if (s3) stageB(t + 3, bs);
        BAR();
        if (r1) { WAIT_LGKM(12); } else { WAIT_LGKM0(); }
        __builtin_amdgcn_s_setprio(1);
        MFMA16(a1, b, acc[1]);
        __builtin_amdgcn_s_setprio(0);
        if (r1) {
#pragma unroll
            for (int ni = 0; ni < 2; ++ni) { b[ni][0] = bn[ni][0]; b[ni][1] = bn[ni][1]; }
        }
        if (tail) { WAIT_VM(0); } else { WAIT_VM(4); }
        BAR();
        bs = bs2;
    }

    const int b_  = m0 >> 9;
    const int h00 = m0 & 511;
    float (*T)[132] = (float(*)[132])lds_s;
#pragma unroll
    for (int q = 0; q < 2; ++q) {
        __syncthreads();
#pragma unroll
        for (int mi = 0; mi < 4; ++mi)
#pragma unroll
        for (int ni = 0; ni < 2; ++ni) {
            int tl = wn * 32 + ni * 16 + lm;
            int hl = wm * 64 + mi * 16 + lk * 4;
            *(float4*)&T[tl][hl] = *(float4*)&acc[q][mi][ni];
        }
        __syncthreads();
        int hg = h00 + q * 128 + (tid & 31) * 4;
        float4 dv = *(const float4*)&Dp[hg];
#pragma unroll
        for (int it = 0; it < 8; ++it) {
            int tl = (tid >> 5) + it * 16;
            int tg = 2 * (n0 + tl) + p;
            size_t gidx = ((size_t)b_ * cL + tg) * cH + hg;
            float4 uv = *(const float4*)&u[gidx];
            float4 yv = *(float4*)&T[tl][(tid & 31) * 4];
            yv.x += dv.x * uv.x;
            yv.y += dv.y * uv.y;
            yv.z += dv.z * uv.z;
            yv.w += dv.w * uv.w;
            *(float4*)&out[gidx] = yv;
        }
    }
}

extern "C" void kernel_launch(void* const* d_in, const int* in_sizes, int n_in,
                              void* d_out, int out_size, void* d_ws, size_t ws_size,
                              hipStream_t stream) {
    const float* u    = (const float*)d_in[0];
    const float* w_re = (const float*)d_in[1];
    const float* w_im = (const float*)d_in[2];
    const float* C_re = (const float*)d_in[3];
    const float* C_im = (const float*)d_in[4];
    const float* Dp   = (const float*)d_in[5];
    const float* dt   = (const float*)d_in[6];
    float* out = (float*)d_out;
    short* Wb  = (short*)d_ws;

    hipLaunchKernelGGL(k_tabs,  dim3(4096), dim3(256), 0, stream, Wb);
    hipLaunchKernelGGL(k_trans, dim3(cL / 64, cH / 64, cB), dim3(256), 0, stream, u, Wb);
    hipLaunchKernelGGL(k_kgen,  dim3(cH), dim3(256), 0, stream,
                       w_re, w_im, C_re, C_im, dt, Wb);
    hipLaunchKernelGGL(k_kfg,   dim3(32, 4), dim3(256), 0, stream, Wb);
    hipLaunchKernelGGL(k_fwd8,  dim3(256), dim3(512), 0, stream, Wb);
    hipLaunchKernelGGL(k_invB,  dim3(256), dim3(512), 0, stream, u, Dp, Wb, out);
}

// Round 15
// 195.277 us; speedup vs baseline: 1.3089x; 1.0201x over previous
//
#include <hip/hip_runtime.h>
#include <hip/hip_bf16.h>
#include <math.h>

// S4DConv via MFMA: B=8, L=2048, H=512, N=64, CH=1
//   r15: 2D XCD clustering (4m x 8n rectangles per XCD) for both GEMMs;
//   k_fwd8 epilogue single-pass short8 (16B) stores. Cores = r14 (read-ahead).

namespace {
constexpr int cB = 8;
constexpr int cL = 2048;
constexpr int cH = 512;
constexpr int cN = 64;
constexpr int M1 = 4095;
constexpr int M2 = 4096;
constexpr int BH = cB * cH;            // 4096
constexpr int MA = BH + cH;            // 4608

constexpr size_t S0   = 2 * ((size_t)cH * cN * 6);
constexpr size_t S_B1 = S0;                           // [4096][2048] paired
constexpr size_t S_A  = S_B1 + (size_t)4096 * 2048;   // [4608][2048]
constexpr size_t S_T2 = S_A  + (size_t)MA * 2048;     // B2 [2][1024][2048]
constexpr size_t S_U  = S_T2 + (size_t)2048 * 4096;   // [4608][4096]: rows<4096 Ae|Ao; 4096+ KF
}

typedef __attribute__((ext_vector_type(8))) short short8;
typedef __attribute__((ext_vector_type(4))) float f32x4;

static __device__ inline short f2bf(float x) {
    __hip_bfloat16 h = __float2bfloat16(x);
    return *reinterpret_cast<short*>(&h);
}
static __device__ inline float bf2f(short s) {
    return __uint_as_float(((unsigned int)(unsigned short)s) << 16);
}
static __device__ __forceinline__ void load_lds16(const short* g, short* l) {
    __builtin_amdgcn_global_load_lds(
        (const __attribute__((address_space(1))) void*)g,
        (__attribute__((address_space(3))) void*)l, 16, 0, 0);
}
#define WAIT_LGKM0() do { asm volatile("s_waitcnt lgkmcnt(0)" ::: "memory"); \
                          __builtin_amdgcn_sched_barrier(0); } while (0)
#define WAIT_LGKM(n) do { asm volatile("s_waitcnt lgkmcnt(" #n ")" ::: "memory"); \
                          __builtin_amdgcn_sched_barrier(0); } while (0)
#define WAIT_VM(n)   do { asm volatile("s_waitcnt vmcnt(" #n ")" ::: "memory"); \
                          __builtin_amdgcn_sched_barrier(0); } while (0)
#define BAR() __builtin_amdgcn_s_barrier()

__global__ __launch_bounds__(256) void k_tabs(short* __restrict__ Wb)
{
    int tid = threadIdx.x;
    if (blockIdx.x < 2048) {              // B1'' rows for DFT j = blockIdx.x
        int j  = blockIdx.x;
        int base = (j < 1024) ? 4 * j : (j == 1024 ? 2 : 4 * (2048 - j) + 2);
        int t0 = tid * 8;
        int p0 = (int)(((long)j * t0) % M1);
        float c, s, cs, ss;
        sincosf((6.283185307179586f / (float)M1) * (float)p0, &s, &c);
        sincosf((6.283185307179586f / (float)M1) * (float)j,  &ss, &cs);
        short8 vc, vs;
#pragma unroll
        for (int i = 0; i < 8; ++i) {
            vc[i] = f2bf(c); vs[i] = f2bf(s);
            float tr = c * cs - s * ss;
            s = c * ss + s * cs;
            c = tr;
        }
        *(short8*)&Wb[S_B1 + (size_t)base       * 2048 + t0] = vc;
        *(short8*)&Wb[S_B1 + (size_t)(base + 1) * 2048 + t0] = vs;
    } else {                              // B2 parity rows
        int r   = blockIdx.x - 2048;
        int p   = r >> 10, tau = r & 1023;
        int t   = 2 * tau + p;
        int k0  = tid * 8;
        float stepang = (6.283185307179586f / (float)M2) * (float)t;
        float cs, ss; sincosf(stepang, &ss, &cs);
        short8 v;
        if (k0 < 1024) {                  // cos chunk
            int ph = (k0 * t) & (M2 - 1);
            float c, s; sincosf((6.283185307179586f / (float)M2) * (float)ph, &s, &c);
#pragma unroll
            for (int i = 0; i < 8; ++i) {
                v[i] = f2bf(c);
                float tr = c * cs - s * ss;
                s = c * ss + s * cs;
                c = tr;
            }
        } else {                          // sin chunk, j=k-1024; k==1024 special
            int j0 = k0 - 1024;
            int ph = (j0 * t) & (M2 - 1);
            float c, s; sincosf((6.283185307179586f / (float)M2) * (float)ph, &s, &c);
#pragma unroll
            for (int i = 0; i < 8; ++i) {
                int k = k0 + i;
                v[i] = (k == 1024) ? f2bf((tau & 1) ? -1.f : 1.f) : f2bf(s);
                float tr = c * cs - s * ss;
                s = c * ss + s * cs;
                c = tr;
            }
        }
        *(short8*)&Wb[S_T2 + (size_t)r * 2048 + k0] = v;
    }
}

__global__ __launch_bounds__(256) void k_trans(const float* __restrict__ u,
                                               short* __restrict__ Wb)
{
    __shared__ float tile[64][65];
    int t0 = blockIdx.x * 64;
    int h0 = blockIdx.y * 64;
    int b  = blockIdx.z;
    int cx = threadIdx.x & 63, r0 = threadIdx.x >> 6;
#pragma unroll
    for (int i = 0; i < 16; ++i) {
        int row = r0 + i * 4;
        tile[row][cx] = u[((size_t)b * cL + t0 + row) * cH + h0 + cx];
    }
    __syncthreads();
    short* A = Wb + S_A;
#pragma unroll
    for (int i = 0; i < 16; ++i) {
        int hrow = r0 + i * 4;
        A[(size_t)(b * cH + h0 + hrow) * 2048 + t0 + cx] = f2bf(tile[cx][hrow]);
    }
}

__global__ __launch_bounds__(256) void k_kgen(
    const float* __restrict__ w_re, const float* __restrict__ w_im,
    const float* __restrict__ C_re, const float* __restrict__ C_im,
    const float* __restrict__ dt, short* __restrict__ Wb)
{
    __shared__ float md[cN * 6];
    int h = blockIdx.x, tid = threadIdx.x;
    if (tid < cN) {
        int idx = h * cN + tid;
        double dtv = dt[h];
        double wr = w_re[idx], wi = w_im[idx];
        double ar = wr * dtv, ai = wi * dtv;
        double er = exp(ar);
        double zs, zc; sincos(ai, &zs, &zc);
        double zr = er * zc, zi = er * zs;
        double nr = zr - 1.0, ni = zi;
        double inv = 1.0 / (wr * wr + wi * wi);
        double gr = (nr * wr + ni * wi) * inv;
        double gi = (ni * wr - nr * wi) * inv;
        double cr = C_re[idx], ci = C_im[idx];
        md[tid*6+0] = (float)(cr * gr - ci * gi);
        md[tid*6+1] = (float)(cr * gi + ci * gr);
        md[tid*6+2] = (float)zr; md[tid*6+3] = (float)zi;
        md[tid*6+4] = (float)ar; md[tid*6+5] = (float)ai;
    }
    __syncthreads();
    int t0 = tid * 8;
    float acc[8] = {0.f, 0.f, 0.f, 0.f, 0.f, 0.f, 0.f, 0.f};
    for (int n = 0; n < cN; ++n) {
        float csr = md[n*6+0], csi = md[n*6+1];
        float zr  = md[n*6+2], zi  = md[n*6+3];
        float ar  = md[n*6+4], ai  = md[n*6+5];
        float mag = expf(ar * (float)t0);
        double ph = fmod((double)ai * (double)t0, 6.283185307179586);
        float s, c; sincosf((float)ph, &s, &c);
        float pr = mag * c, pi = mag * s;
#pragma unroll
        for (int i = 0; i < 8; ++i) {
            acc[i] += csr * pr - csi * pi;
            float tr = pr * zr - pi * zi;
            pi = pr * zi + pi * zr;
            pr = tr;
        }
    }
    short8 v;
#pragma unroll
    for (int i = 0; i < 8; ++i) v[i] = f2bf(2.f * acc[i]);
    *reinterpret_cast<short8*>(&Wb[S_A + (size_t)(BH + h) * 2048 + t0]) = v;
}

#define MFMA16(AR, BR, ACC) \
    _Pragma("unroll") for (int kk = 0; kk < 2; ++kk) \
    _Pragma("unroll") for (int ni = 0; ni < 2; ++ni) \
    _Pragma("unroll") for (int mi = 0; mi < 4; ++mi) \
        ACC[mi][ni] = __builtin_amdgcn_mfma_f32_16x16x32_bf16(AR[mi][kk], BR[ni][kk], ACC[mi][ni], 0, 0, 0);

// ------- 256x256 core with fragment read-ahead (proven r14) -----------------
__device__ __forceinline__ void gemm8p_core(
    const short* __restrict__ Ag, int lda,
    const short* __restrict__ Bg, int ldb,
    int m0, int n0, int nt, short* lds, f32x4 (&acc)[4][4][2])
{
    const int tid  = threadIdx.x;
    const int wave = tid >> 6, lane = tid & 63;
    const int wm = wave >> 2, wn = wave & 3;
    const int lm = lane & 15, lk = lane >> 4;
    const int srow8 = lane >> 3;
    const int scol  = (lane & 7) * 8;

    auto stage = [&](const short* G, int ldg, int row0, int half, int kt, int sb) {
        short* l0 = lds + sb + (size_t)((kt & 1) * 2 + half) * 8192;
#pragma unroll
        for (int q = 0; q < 2; ++q) {
            int chunk = wave * 2 + q;
            int r = chunk * 8 + srow8;
            int c = scol ^ ((r & 7) << 3);
            load_lds16(G + (size_t)(row0 + half * 128 + r) * ldg + kt * 64 + c,
                       l0 + chunk * 512);
        }
    };
    auto rdA = [&](int qa, int kt, int mi, int kk) -> short8 {
        int rl = wm * 64 + mi * 16 + lm;
        int c  = (kk * 32 + lk * 8) ^ ((rl & 7) << 3);
        return *(const short8*)(lds + (size_t)((kt & 1) * 2 + qa) * 8192 + rl * 64 + c);
    };
    auto rdB = [&](int qb, int kt, int ni, int kk) -> short8 {
        int rl = wn * 32 + ni * 16 + lm;
        int c  = (kk * 32 + lk * 8) ^ ((rl & 7) << 3);
        return *(const short8*)(lds + 32768 + (size_t)((kt & 1) * 2 + qb) * 8192 + rl * 64 + c);
    };

    // prologue: tiles 0,1 fully staged (16 loads)
    stage(Ag, lda, m0, 0, 0, 0);
    stage(Bg, ldb, n0, 0, 0, 32768);
    stage(Bg, ldb, n0, 1, 0, 32768);
    stage(Ag, lda, m0, 1, 0, 0);
    stage(Ag, lda, m0, 0, 1, 0);
    stage(Bg, ldb, n0, 0, 1, 32768);
    stage(Bg, ldb, n0, 1, 1, 32768);
    stage(Ag, lda, m0, 1, 1, 0);
    WAIT_VM(12);                 // A0(0),B0(0) landed
    BAR();

    short8 a0[4][2], a1[4][2], b0[2][2], b1[2][2], b0n[2][2];
#pragma unroll
    for (int mi = 0; mi < 4; ++mi) { a0[mi][0] = rdA(0, 0, mi, 0); a0[mi][1] = rdA(0, 0, mi, 1); }
#pragma unroll
    for (int ni = 0; ni < 2; ++ni) { b0[ni][0] = rdB(0, 0, ni, 0); b0[ni][1] = rdB(0, 0, ni, 1); }
    WAIT_VM(10);                 // B1(0) landed
    BAR();

    for (int t = 0; t < nt; ++t) {
        const bool st = (t + 2 < nt);
        const bool rd = (t + 1 < nt);
        // ---- P0: rd-ahead b1(t); MFMA Q00(a0,b0) ----
#pragma unroll
        for (int ni = 0; ni < 2; ++ni) { b1[ni][0] = rdB(1, t, ni, 0); b1[ni][1] = rdB(1, t, ni, 1); }
        BAR();
        WAIT_LGKM(4);
        __builtin_amdgcn_s_setprio(1);
        MFMA16(a0, b0, acc[0]);
        __builtin_amdgcn_s_setprio(0);
        if (rd) { WAIT_VM(8); } else { WAIT_VM(0); }
        BAR();
        // ---- P1: rd-ahead a1(t); stage A0,B0(t+2); MFMA Q01(a0,b1) ----
#pragma unroll
        for (int mi = 0; mi < 4; ++mi) { a1[mi][0] = rdA(1, t, mi, 0); a1[mi][1] = rdA(1, t, mi, 1); }
        if (st) { stage(Ag, lda, m0, 0, t + 2, 0); stage(Bg, ldb, n0, 0, t + 2, 32768); }
        BAR();
        WAIT_LGKM(8);
        __builtin_amdgcn_s_setprio(1);
        MFMA16(a0, b1, acc[1]);
        __builtin_amdgcn_s_setprio(0);
        BAR();
        // ---- P2: stage B1(t+2); MFMA Q11(a1,b1) ----
        if (st) stage(Bg, ldb, n0, 1, t + 2, 32768);
        BAR();
        WAIT_LGKM0();
        __builtin_amdgcn_s_setprio(1);
        MFMA16(a1, b1, acc[3]);
        __builtin_amdgcn_s_setprio(0);
        if (st) { WAIT_VM(10); } else { WAIT_VM(0); }
        BAR();
        // ---- P3: rd-ahead a0,b0n(t+1); stage A1(t+2); MFMA Q10(a1,b0) ----
        if (rd) {
#pragma unroll
            for (int mi = 0; mi < 4; ++mi) { a0[mi][0] = rdA(0, t + 1, mi, 0); a0[mi][1] = rdA(0, t + 1, mi, 1); }
#pragma unroll
            for (int ni = 0; ni < 2; ++ni) { b0n[ni][0] = rdB(0, t + 1, ni, 0); b0n[ni][1] = rdB(0, t + 1, ni, 1); }
        }
        if (st) stage(Ag, lda, m0, 1, t + 2, 0);
        BAR();
        __builtin_amdgcn_s_setprio(1);
        MFMA16(a1, b0, acc[2]);
        __builtin_amdgcn_s_setprio(0);
        if (rd) {
#pragma unroll
            for (int ni = 0; ni < 2; ++ni) { b0[ni][0] = b0n[ni][0]; b0[ni][1] = b0n[ni][1]; }
            WAIT_VM(10);
        } else { WAIT_VM(0); }
        BAR();
    }
}

// forward: acc = A_u x B1''^T; epilogue: mix (x KF) + parity fold -> Ae|Ao
__global__ __launch_bounds__(512, 2) void k_fwd8(short* __restrict__ Wb)
{
    __shared__ short lds_s[65536];
    // 2D XCD cluster: xcd covers 4 m-tiles x 8 n-tiles
    int xcd = blockIdx.x & 7, idx = blockIdx.x >> 3;
    const int m0 = (((xcd >> 1) << 2) + (idx >> 3)) * 256;
    const int n0 = (((xcd & 1) << 3) + (idx & 7)) * 256;
    const int tid = threadIdx.x;
    const int wave = tid >> 6, lane = tid & 63;
    const int wm = wave >> 2, wn = wave & 3;
    const int lm = lane & 15, lk = lane >> 4;

    f32x4 acc[4][4][2] = {};
    gemm8p_core(Wb + S_A, 2048, Wb + S_B1, 2048, m0, n0, 32, lds_s, acc);

    short* Uw = Wb + S_U;
    const short* KF = Wb + S_U;
    short (*M)[136] = (short(*)[136])lds_s;
    for (int q = 0; q < 4; ++q) {
        __syncthreads();
#pragma unroll
        for (int mi = 0; mi < 4; ++mi)
#pragma unroll
        for (int ni = 0; ni < 2; ++ni)
#pragma unroll
        for (int r = 0; r < 4; ++r)
            M[wm * 64 + mi * 16 + lk * 4 + r][wn * 32 + ni * 16 + lm] =
                f2bf(acc[q][mi][ni][r]);
        __syncthreads();
        // single pass: 4 threads/row x 8 pairs -> short8 (16B) stores
        const int pq0 = (n0 >> 2) + (q & 1) * 32;
        int rl = tid >> 2;
        int cp = (tid & 3) * 8;
        int rowg = m0 + (q >> 1) * 128 + rl;
        int h = rowg & (cH - 1);
        int colg = n0 + (q & 1) * 128 + cp * 4;
        short8 kf4[4], m4[4];
#pragma unroll
        for (int w = 0; w < 4; ++w) {
            kf4[w] = *(const short8*)&KF[(size_t)(4096 + h) * 4096 + colg + w * 8];
            m4[w]  = *(const short8*)&M[rl][cp * 4 + w * 8];
        }
        short8 vce, vse, vco, vso;
#pragma unroll
        for (int i = 0; i < 8; ++i) {
            int w = i >> 1, o = (i & 1) * 4;
            float C  = bf2f(m4[w][o]),   S  = bf2f(m4[w][o+1]);
            float C2 = bf2f(m4[w][o+2]), S2 = bf2f(m4[w][o+3]);
            float Ck  = bf2f(kf4[w][o]),   Sk  = bf2f(kf4[w][o+1]);
            float Ck2 = bf2f(kf4[w][o+2]), Sk2 = bf2f(kf4[w][o+3]);
            int pp = pq0 + cp + i;
            float scp = (pp == 0 ? 1.0f : 2.0f) * (1.0f / (float)M2);
            float scq = 2.0f / (float)M2;
            float yrp = scp * (Ck * C - Sk * S);
            float yip = scp * (Ck * S + Sk * C);
            float yrq = scq * (Ck2 * C2 - Sk2 * S2);
            float yiq = scq * (Ck2 * S2 + Sk2 * C2);
            float ce, co, se, so;
            if (pp == 0) { ce = yrp; co = yrp; se = yrq; so = yiq; }
            else { ce = yrp + yrq; co = yrp - yrq; se = yip - yiq; so = yip + yiq; }
            vce[i] = f2bf(ce); vco[i] = f2bf(co);
            vse[i] = f2bf(se); vso[i] = f2bf(so);
        }
        size_t base = (size_t)rowg * 4096;
        int kx = pq0 + cp;
        *(short8*)&Uw[base + kx]        = vce;
        *(short8*)&Uw[base + 1024 + kx] = vse;
        *(short8*)&Uw[base + 2048 + kx] = vco;
        *(short8*)&Uw[base + 3072 + kx] = vso;
    }
}

// KF rows: U[4096+h] = A_k x B1''^T
__global__ __launch_bounds__(256, 2) void k_kfg(short* __restrict__ Wb)
{
    __shared__ __align__(16) short As[128][32];
    __shared__ __align__(16) short Bs[128][32];
    const short* A = Wb + S_A;
    const short* B = Wb + S_B1;
    short* U = Wb + S_U;
    const int tid = threadIdx.x;
    const int m0 = 4096 + blockIdx.y * 128, n0 = blockIdx.x * 128;
    const int wave = tid >> 6, lane = tid & 63;
    const int wr = wave >> 1, wc = wave & 1;
    const int lm = lane & 15, lk = lane >> 4;
    const int srow = lane >> 2, scol = (lane & 3) * 8;

    f32x4 acc[4][4] = {};
    for (int k0 = 0; k0 < 2048; k0 += 32) {
        __syncthreads();
        {
            int c0 = wave * 2;
            load_lds16(&A[(size_t)(m0 + c0*16      + srow)*2048 + k0 + scol], &As[c0*16][0]);
            load_lds16(&A[(size_t)(m0 + c0*16 + 16 + srow)*2048 + k0 + scol], &As[c0*16+16][0]);
            load_lds16(&B[(size_t)(n0 + c0*16      + srow)*2048 + k0 + scol], &Bs[c0*16][0]);
            load_lds16(&B[(size_t)(n0 + c0*16 + 16 + srow)*2048 + k0 + scol], &Bs[c0*16+16][0]);
        }
        __syncthreads();
        short8 a[4];
#pragma unroll
        for (int mi = 0; mi < 4; ++mi)
            a[mi] = *(const short8*)&As[wr*64 + mi*16 + lm][lk*8];
#pragma unroll
        for (int ni = 0; ni < 4; ++ni) {
            short8 b = *(const short8*)&Bs[wc*64 + ni*16 + lm][lk*8];
#pragma unroll
            for (int mi = 0; mi < 4; ++mi)
                acc[mi][ni] = __builtin_amdgcn_mfma_f32_16x16x32_bf16(a[mi], b, acc[mi][ni], 0, 0, 0);
        }
    }
#pragma unroll
    for (int mi = 0; mi < 4; ++mi)
#pragma unroll
    for (int ni = 0; ni < 4; ++ni)
#pragma unroll
    for (int r = 0; r < 4; ++r) {
        int row = m0 + wr*64 + mi*16 + lk*4 + r;
        int col = n0 + wc*64 + ni*16 + lm;
        U[(size_t)row * 4096 + col] = f2bf(acc[mi][ni][r]);
    }
}

// inverse: per parity p, y[2tau+p] = A(e/o) x B2_p^T, K=2048, BM=256 x BN=128
__global__ __launch_bounds__(512, 1) void k_invB(const float* __restrict__ u,
                                                 const float* __restrict__ Dp,
                                                 short* __restrict__ Wb,
                                                 float* __restrict__ out)
{
    __shared__ short lds_s[57344];   // 112 KB
    // 2D XCD cluster: xcd covers 4 m-tiles x 8 n-jobs
    int xcd = blockIdx.x & 7, idx = blockIdx.x >> 3;
    const int m0 = ((((xcd >> 1) << 2) + (idx >> 3))) * 256;   // bh
    const int nj = ((xcd & 1) << 3) + (idx & 7);               // 0..15
    const int p  = nj >> 3;
    const int n0 = (nj & 7) * 128;                             // tau0
    const int tid = threadIdx.x;
    const int wave = tid >> 6, lane = tid & 63;
    const int wm = wave >> 2, wn = wave & 3;
    const int lm = lane & 15, lk = lane >> 4;
    const int srow8 = lane >> 3;
    const int scol  = (lane & 7) * 8;
    constexpr int nt = 32;
    short* lds = lds_s;
    const short* Ag = Wb + S_U + (size_t)p * 2048;           // Ae|Ao, lda 4096
    const short* Bg = Wb + S_T2 + (size_t)p * 1024 * 2048;   // [1024][2048]

    auto stageA = [&](int half, int kt) {
        short* l0 = lds + (size_t)((kt & 1) * 2 + half) * 8192;
#pragma unroll
        for (int q = 0; q < 2; ++q) {
            int chunk = wave * 2 + q;
            int r = chunk * 8 + srow8;
            int c = scol ^ ((r & 7) << 3);
            load_lds16(Ag + (size_t)(m0 + half * 128 + r) * 4096 + kt * 64 + c,
                       l0 + chunk * 512);
        }
    };
    auto stageB = [&](int kt, int slot) {
        short* l0 = lds + 32768 + (size_t)slot * 8192;
#pragma unroll
        for (int q = 0; q < 2; ++q) {
            int chunk = wave * 2 + q;
            int r = chunk * 8 + srow8;
            int c = scol ^ ((r & 7) << 3);
            load_lds16(Bg + (size_t)(n0 + r) * 2048 + kt * 64 + c,
                       l0 + chunk * 512);
        }
    };
    auto rdA = [&](int half, int kt, int mi, int kk) -> short8 {
        int rl = wm * 64 + mi * 16 + lm;
        int c  = (kk * 32 + lk * 8) ^ ((rl & 7) << 3);
        return *(const short8*)(lds + (size_t)((kt & 1) * 2 + half) * 8192 + rl * 64 + c);
    };
    auto rdB = [&](int slot, int ni, int kk) -> short8 {
        int rl = wn * 32 + ni * 16 + lm;
        int c  = (kk * 32 + lk * 8) ^ ((rl & 7) << 3);
        return *(const short8*)(lds + 32768 + (size_t)slot * 8192 + rl * 64 + c);
    };

    f32x4 acc[2][4][2] = {};

    // prologue: A0(0),B(0),A1(0),A0(1),B(1),B(2)  [12 loads]
    stageA(0, 0);
    stageB(0, 0);
    stageA(1, 0);
    stageA(0, 1);
    stageB(1, 1);
    stageB(2, 2);
    WAIT_VM(8);                  // A0(0),B(0) landed
    BAR();
    short8 a0[4][2], a1[4][2], b[2][2], bn[2][2];
#pragma unroll
    for (int mi = 0; mi < 4; ++mi) { a0[mi][0] = rdA(0, 0, mi, 0); a0[mi][1] = rdA(0, 0, mi, 1); }
#pragma unroll
    for (int ni = 0; ni < 2; ++ni) { b[ni][0] = rdB(0, ni, 0); b[ni][1] = rdB(0, ni, 1); }
    WAIT_VM(4);                  // A1(0) landed
    BAR();

    int bs = 0;
    for (int t = 0; t < nt; ++t) {
        const bool r1 = (t + 1 < nt);
        const bool s2 = (t + 2 < nt);
        const bool s3 = (t + 3 < nt);
        const bool tail = (t >= nt - 3);
        const int bs2 = (bs == 2) ? 0 : bs + 1;
        // ---- P0: rd-ahead a1(t); stage A1(t+1); MFMA(a0,b) ----
#pragma unroll
        for (int mi = 0; mi < 4; ++mi) { a1[mi][0] = rdA(1, t, mi, 0); a1[mi][1] = rdA(1, t, mi, 1); }
        if (r1) stageA(1, t + 1);
        BAR();
        WAIT_LGKM(8);
        __builtin_amdgcn_s_setprio(1);
        MFMA16(a0, b, acc[0]);
        __builtin_amdgcn_s_setprio(0);
        if (tail) { WAIT_VM(0); } else { WAIT_VM(4); }
        BAR();
        // ---- P1: rd-ahead a0(t+1),bn(t+1); stage A0(t+2),B(t+3); MFMA(a1,b) ----
        if (r1) {
#pragma unroll
            for (int mi = 0; mi < 4; ++mi) { a0[mi][0] = rdA(0, t + 1, mi, 0); a0[mi][1] = rdA(0, t + 1, mi, 1); }
#pragma unroll
            for (int ni = 0; ni < 2; ++ni) { bn[ni][0] = rdB(bs2, ni, 0); bn[ni][1] = rdB(bs2, ni, 1); }
        }
        if (s2) stageA(0, t + 2);
        if (s3) stageB(t + 3, bs);
        BAR();
        if (r1) { WAIT_LGKM(12); } else { WAIT_LGKM0(); }
        __builtin_amdgcn_s_setprio(1);
        MFMA16(a1, b, acc[1]);
        __builtin_amdgcn_s_setprio(0);
        if (r1) {
#pragma unroll
            for (int ni = 0; ni < 2; ++ni) { b[ni][0] = bn[ni][0]; b[ni][1] = bn[ni][1]; }
        }
        if (tail) { WAIT_VM(0); } else { WAIT_VM(4); }
        BAR();
        bs = bs2;
    }

    const int b_  = m0 >> 9;
    const int h00 = m0 & 511;
    float (*T)[132] = (float(*)[132])lds_s;
#pragma unroll
    for (int q = 0; q < 2; ++q) {
        __syncthreads();
#pragma unroll
        for (int mi = 0; mi < 4; ++mi)
#pragma unroll
        for (int ni = 0; ni < 2; ++ni) {
            int tl = wn * 32 + ni * 16 + lm;
            int hl = wm * 64 + mi * 16 + lk * 4;
            *(float4*)&T[tl][hl] = *(float4*)&acc[q][mi][ni];
        }
        __syncthreads();
        int hg = h00 + q * 128 + (tid & 31) * 4;
        float4 dv = *(const float4*)&Dp[hg];
#pragma unroll
        for (int it = 0; it < 8; ++it) {
            int tl = (tid >> 5) + it * 16;
            int tg = 2 * (n0 + tl) + p;
            size_t gidx = ((size_t)b_ * cL + tg) * cH + hg;
            float4 uv = *(const float4*)&u[gidx];
            float4 yv = *(float4*)&T[tl][(tid & 31) * 4];
            yv.x += dv.x * uv.x;
            yv.y += dv.y * uv.y;
            yv.z += dv.z * uv.z;
            yv.w += dv.w * uv.w;
            *(float4*)&out[gidx] = yv;
        }
    }
}

extern "C" void kernel_launch(void* const* d_in, const int* in_sizes, int n_in,
                              void* d_out, int out_size, void* d_ws, size_t ws_size,
                              hipStream_t stream) {
    const float* u    = (const float*)d_in[0];
    const float* w_re = (const float*)d_in[1];
    const float* w_im = (const float*)d_in[2];
    const float* C_re = (const float*)d_in[3];
    const float* C_im = (const float*)d_in[4];
    const float* Dp   = (const float*)d_in[5];
    const float* dt   = (const float*)d_in[6];
    float* out = (float*)d_out;
    short* Wb  = (short*)d_ws;

    hipLaunchKernelGGL(k_tabs,  dim3(4096), dim3(256), 0, stream, Wb);
    hipLaunchKernelGGL(k_trans, dim3(cL / 64, cH / 64, cB), dim3(256), 0, stream, u, Wb);
    hipLaunchKernelGGL(k_kgen,  dim3(cH), dim3(256), 0, stream,
                       w_re, w_im, C_re, C_im, dt, Wb);
    hipLaunchKernelGGL(k_kfg,   dim3(32, 4), dim3(256), 0, stream, Wb);
    hipLaunchKernelGGL(k_fwd8,  dim3(256), dim3(512), 0, stream, Wb);
    hipLaunchKernelGGL(k_invB,  dim3(256), dim3(512), 0, stream, u, Dp, Wb, out);
}